// Round 19
// baseline (175.650 us; speedup 1.0000x reference)
//
#include <hip/hip_runtime.h>
#include <hip/hip_bf16.h>
#include <math.h>

#define B2    2048
#define NPM   30
#define EPM   120

typedef __attribute__((ext_vector_type(8))) short short8;
typedef __attribute__((ext_vector_type(4))) float f32x4;

__device__ __forceinline__ ushort f2bf(float x) {
  unsigned u = __float_as_uint(x);
  return (ushort)((u + 0x7FFFu + ((u >> 16) & 1u)) >> 16);
}
__device__ __forceinline__ float bf2f(ushort h) {
  return __uint_as_float(((unsigned)h) << 16);
}

// swizzled byte offsets: 128B rows (per-chunk tiles) and 256B rows (full-K A)
__device__ __forceinline__ int swz128(int r, int kb) { return r * 128 + (kb ^ ((r & 7) << 4)); }
__device__ __forceinline__ int swz256(int r, int kb) { return r * 256 + (kb ^ ((r & 15) << 4)); }

// ---------------------------------------------------------------------------
// prep_all: 8 weight preps in one launch. W[Kreal][N] -> bf16 split [N][Kpad].
// ---------------------------------------------------------------------------
struct PrepDescs {
  const float* W[8];
  ushort* hi[8];
  ushort* lo[8];
  int Kreal[8], Kpad[8], N[8];
  int blk0[9];
};

__global__ __launch_bounds__(256) void prep_all_kernel(PrepDescs d)
{
  int b = blockIdx.x;
  int di = 0;
  #pragma unroll
  for (int j = 1; j < 8; ++j) if (b >= d.blk0[j]) di = j;
  int idx = (b - d.blk0[di]) * 256 + threadIdx.x;
  int Kp8 = d.Kpad[di] >> 3;
  int tot = d.N[di] * Kp8;
  if (idx >= tot) return;
  int n = idx / Kp8;
  int k8 = (idx - n * Kp8) << 3;
  const float* W = d.W[di];
  ushort* hi = d.hi[di];
  ushort* lo = d.lo[di];
  int Kreal = d.Kreal[di], Kpad = d.Kpad[di], N = d.N[di];
  #pragma unroll
  for (int j = 0; j < 8; ++j) {
    int k = k8 + j;
    float x = (k < Kreal) ? W[(long)k * N + n] : 0.f;
    ushort h = f2bf(x);
    hi[(long)n * Kpad + k] = h;
    lo[(long)n * Kpad + k] = f2bf(x - bf2f(h));
  }
}

// We2[32][128][128] -> per-k transposed bf16 split hi/lo[k][n][d]
__global__ __launch_bounds__(256) void prep_we2_kernel(
    const float* __restrict__ We2, ushort* __restrict__ hi, ushort* __restrict__ lo)
{
  int idx = blockIdx.x * 256 + threadIdx.x;
  int k = idx >> 11;
  int rem = idx & 2047;
  int n = rem >> 4;
  int d8 = (rem & 15) << 3;
  #pragma unroll
  for (int j = 0; j < 8; ++j) {
    int d = d8 + j;
    float x = We2[k * 16384 + d * 128 + n];
    ushort h = f2bf(x);
    hi[k * 16384 + n * 128 + d] = h;
    lo[k * 16384 + n * 128 + d] = f2bf(x - bf2f(h));
  }
}

// ---------------------------------------------------------------------------
// grufuse v2 (validated round 15): 32x32 tiles, 512 blocks.
// ---------------------------------------------------------------------------
__global__ __launch_bounds__(256, 4) void grufuse_kernel(
    const float* __restrict__ aggA, const float* __restrict__ aggB,
    const float* __restrict__ zb, const float* __restrict__ bnn,
    const float* __restrict__ xp,
    const ushort* __restrict__ Wihh, const ushort* __restrict__ Wihl,
    const float* __restrict__ bih,
    const ushort* __restrict__ Whhh, const ushort* __restrict__ Whhl,
    const float* __restrict__ bhh,
    float* __restrict__ xnew)
{
  __shared__ __align__(16) char A1h[8192], A1l[8192];   // x_in 32 x 256B swz
  __shared__ __align__(16) char A2h[8192], A2l[8192];   // xp   32 x 256B swz
  __shared__ __align__(16) char Bh[4096], Bl[4096];     // W chunk 32 x 128B swz
  const int tid = threadIdx.x;
  const int w = tid >> 6, l = tid & 63;
  const int rt = blockIdx.x >> 2;          // row-tile (32 rows)
  const int qt = blockIdx.x & 3;           // gate-col quarter (32 cols)
  const long rowBase = (long)rt * 32;
  const int rw = w & 1;                    // row-wave (16 rows)
  const int cs = w >> 1;                   // col-subtile (16 cols)
  const int ar = rw * 16 + (l & 15);
  const int crow = rw * 16 + ((l >> 4) << 2);

  // stage A1 = relu(agg + zb_i + zb_{i+B} + bnn) and A2 = xp, bf16-split
  #pragma unroll
  for (int q = 0; q < 4; ++q) {
    int t = tid + 256 * q;                 // 0..1023
    int r = t >> 5, k4 = (t & 31) << 2;
    long gr = rowBase + r;
    long i = (gr < B2) ? gr : (gr - B2);
    float4 za = *(const float4*)&zb[i * 128 + k4];
    float4 zc = *(const float4*)&zb[(i + B2) * 128 + k4];
    float4 bn = *(const float4*)&bnn[k4];
    const float* ap = (gr < B2) ? &aggA[i * 128 + k4] : &aggB[i * 128 + k4];
    float4 ag = *(const float4*)ap;
    float4 xv;
    xv.x = fmaxf(ag.x + za.x + zc.x + bn.x, 0.f);
    xv.y = fmaxf(ag.y + za.y + zc.y + bn.y, 0.f);
    xv.z = fmaxf(ag.z + za.z + zc.z + bn.z, 0.f);
    xv.w = fmaxf(ag.w + za.w + zc.w + bn.w, 0.f);
    ushort4 h4, l4;
    h4.x = f2bf(xv.x); l4.x = f2bf(xv.x - bf2f(h4.x));
    h4.y = f2bf(xv.y); l4.y = f2bf(xv.y - bf2f(h4.y));
    h4.z = f2bf(xv.z); l4.z = f2bf(xv.z - bf2f(h4.z));
    h4.w = f2bf(xv.w); l4.w = f2bf(xv.w - bf2f(h4.w));
    *(ushort4*)(A1h + swz256(r, k4 * 2)) = h4;
    *(ushort4*)(A1l + swz256(r, k4 * 2)) = l4;
    float4 pv = *(const float4*)&xp[gr * 128 + k4];
    h4.x = f2bf(pv.x); l4.x = f2bf(pv.x - bf2f(h4.x));
    h4.y = f2bf(pv.y); l4.y = f2bf(pv.y - bf2f(h4.y));
    h4.z = f2bf(pv.z); l4.z = f2bf(pv.z - bf2f(h4.z));
    h4.w = f2bf(pv.w); l4.w = f2bf(pv.w - bf2f(h4.w));
    *(ushort4*)(A2h + swz256(r, k4 * 2)) = h4;
    *(ushort4*)(A2l + swz256(r, k4 * 2)) = l4;
  }
  __syncthreads();

  f32x4 rg = (f32x4){0,0,0,0}, zg = (f32x4){0,0,0,0};

  for (int gate = 0; gate < 3; ++gate) {
    f32x4 gi = (f32x4){0,0,0,0}, gh = (f32x4){0,0,0,0};
    for (int src = 0; src < 2; ++src) {
      const ushort* Wh = src ? Whhh : Wihh;
      const ushort* Wl = src ? Whhl : Wihl;
      const char* Ah = src ? A2h : A1h;
      const char* Al = src ? A2l : A1l;
      for (int k0 = 0; k0 < 128; k0 += 64) {
        __syncthreads();
        {
          int n = tid >> 3, k8 = (tid & 7) << 3;   // 32 rows x 8 chunks = 256
          long wrow = (long)(gate * 128 + qt * 32 + n);
          *(uint4*)(Bh + swz128(n, k8 * 2)) = *(const uint4*)&Wh[wrow * 128 + k0 + k8];
          *(uint4*)(Bl + swz128(n, k8 * 2)) = *(const uint4*)&Wl[wrow * 128 + k0 + k8];
        }
        __syncthreads();
        f32x4 a = (src == 0) ? gi : gh;
        #pragma unroll
        for (int ks = 0; ks < 2; ++ks) {
          const int ko = ks * 32 + (l >> 4) * 8;
          short8 ah  = *(const short8*)(Ah + swz256(ar, (k0 + ko) * 2));
          short8 al8 = *(const short8*)(Al + swz256(ar, (k0 + ko) * 2));
          const int c = cs * 16 + (l & 15);
          short8 bh  = *(const short8*)(Bh + swz128(c, ko * 2));
          short8 bl8 = *(const short8*)(Bl + swz128(c, ko * 2));
          a = __builtin_amdgcn_mfma_f32_16x16x32_bf16(al8, bh, a, 0, 0, 0);
          a = __builtin_amdgcn_mfma_f32_16x16x32_bf16(ah, bl8, a, 0, 0, 0);
          a = __builtin_amdgcn_mfma_f32_16x16x32_bf16(ah, bh, a, 0, 0, 0);
        }
        if (src == 0) gi = a; else gh = a;
      }
    }
    int cg = qt * 32 + cs * 16 + (l & 15);
    float bi = bih[gate * 128 + cg], bh2 = bhh[gate * 128 + cg];
    #pragma unroll
    for (int i = 0; i < 4; ++i) {
      float a = gi[i] + bi;
      float b = gh[i] + bh2;
      if (gate == 0) {
        rg[i] = 1.f / (1.f + expf(-(a + b)));
      } else if (gate == 1) {
        zg[i] = 1.f / (1.f + expf(-(a + b)));
      } else {
        float ng = tanhf(a + rg[i] * b);
        long row = rowBase + crow + i;
        float h = xp[row * 128 + cg];
        xnew[row * 128 + cg] = (1.f - zg[i]) * ng + zg[i] * h;
      }
    }
  }
}

// ---------------------------------------------------------------------------
// xpzb: xp = relu(xcat@Wp+bp); zb = xp@be2 (xp kept in LDS, no re-read).
// ---------------------------------------------------------------------------
__global__ __launch_bounds__(256) void xpzb_kernel(
    const float* __restrict__ xcat,
    const ushort* __restrict__ Wph, const ushort* __restrict__ Wpl,
    const float* __restrict__ bp,
    const ushort* __restrict__ be2h, const ushort* __restrict__ be2l,
    float* __restrict__ xp, float* __restrict__ zb)
{
  __shared__ __align__(16) char AhB[16384], AlB[16384];
  __shared__ __align__(16) char BhB[16384], BlB[16384];
  const int tid = threadIdx.x;
  const int w = tid >> 6, l = tid & 63;
  const long rowBase = (long)blockIdx.x * 64;
  const int ar = w * 16 + (l & 15);
  const int crow = w * 16 + ((l >> 4) << 2);

  #pragma unroll
  for (int q = 0; q < 8; ++q) {
    int t = tid + 256 * q;
    int r = t >> 5, k4 = (t & 31) << 2;
    float4 v = *(const float4*)&xcat[(rowBase + r) * 128 + k4];
    ushort4 h4, l4;
    h4.x = f2bf(v.x); l4.x = f2bf(v.x - bf2f(h4.x));
    h4.y = f2bf(v.y); l4.y = f2bf(v.y - bf2f(h4.y));
    h4.z = f2bf(v.z); l4.z = f2bf(v.z - bf2f(h4.z));
    h4.w = f2bf(v.w); l4.w = f2bf(v.w - bf2f(h4.w));
    *(ushort4*)(AhB + swz256(r, k4 * 2)) = h4;
    *(ushort4*)(AlB + swz256(r, k4 * 2)) = l4;
  }
  __syncthreads();

  f32x4 acc[8];
  #pragma unroll
  for (int fc = 0; fc < 8; ++fc) acc[fc] = (f32x4){0.f, 0.f, 0.f, 0.f};
  for (int k0 = 0; k0 < 128; k0 += 64) {
    #pragma unroll
    for (int q = 0; q < 4; ++q) {
      int lin = tid + 256 * q;
      int n = lin >> 3, k8 = (lin & 7) << 3;
      *(uint4*)(BhB + swz128(n, k8 * 2)) = *(const uint4*)&Wph[n * 128 + k0 + k8];
      *(uint4*)(BlB + swz128(n, k8 * 2)) = *(const uint4*)&Wpl[n * 128 + k0 + k8];
    }
    __syncthreads();
    #pragma unroll
    for (int ks = 0; ks < 2; ++ks) {
      const int ko = ks * 32 + (l >> 4) * 8;
      short8 ah  = *(const short8*)(AhB + swz256(ar, (k0 + ko) * 2));
      short8 al8 = *(const short8*)(AlB + swz256(ar, (k0 + ko) * 2));
      #pragma unroll
      for (int fc = 0; fc < 8; ++fc) {
        const int c = fc * 16 + (l & 15);
        short8 bh  = *(const short8*)(BhB + swz128(c, ko * 2));
        short8 bl8 = *(const short8*)(BlB + swz128(c, ko * 2));
        acc[fc] = __builtin_amdgcn_mfma_f32_16x16x32_bf16(al8, bh, acc[fc], 0, 0, 0);
        acc[fc] = __builtin_amdgcn_mfma_f32_16x16x32_bf16(ah, bl8, acc[fc], 0, 0, 0);
        acc[fc] = __builtin_amdgcn_mfma_f32_16x16x32_bf16(ah, bh, acc[fc], 0, 0, 0);
      }
    }
    __syncthreads();
  }

  #pragma unroll
  for (int fc = 0; fc < 8; ++fc) {
    int col = fc * 16 + (l & 15);
    float bv = bp[col];
    #pragma unroll
    for (int i = 0; i < 4; ++i) {
      int lr = crow + i;
      float v = fmaxf(acc[fc][i] + bv, 0.f);
      xp[(rowBase + lr) * 128 + col] = v;
      ushort h = f2bf(v);
      *(ushort*)(AhB + swz256(lr, col * 2)) = h;
      *(ushort*)(AlB + swz256(lr, col * 2)) = f2bf(v - bf2f(h));
    }
  }

  #pragma unroll
  for (int fc = 0; fc < 8; ++fc) acc[fc] = (f32x4){0.f, 0.f, 0.f, 0.f};
  for (int k0 = 0; k0 < 128; k0 += 64) {
    __syncthreads();
    #pragma unroll
    for (int q = 0; q < 4; ++q) {
      int lin = tid + 256 * q;
      int n = lin >> 3, k8 = (lin & 7) << 3;
      *(uint4*)(BhB + swz128(n, k8 * 2)) = *(const uint4*)&be2h[n * 128 + k0 + k8];
      *(uint4*)(BlB + swz128(n, k8 * 2)) = *(const uint4*)&be2l[n * 128 + k0 + k8];
    }
    __syncthreads();
    #pragma unroll
    for (int ks = 0; ks < 2; ++ks) {
      const int ko = ks * 32 + (l >> 4) * 8;
      short8 ah  = *(const short8*)(AhB + swz256(ar, (k0 + ko) * 2));
      short8 al8 = *(const short8*)(AlB + swz256(ar, (k0 + ko) * 2));
      #pragma unroll
      for (int fc = 0; fc < 8; ++fc) {
        const int c = fc * 16 + (l & 15);
        short8 bh  = *(const short8*)(BhB + swz128(c, ko * 2));
        short8 bl8 = *(const short8*)(BlB + swz128(c, ko * 2));
        acc[fc] = __builtin_amdgcn_mfma_f32_16x16x32_bf16(al8, bh, acc[fc], 0, 0, 0);
        acc[fc] = __builtin_amdgcn_mfma_f32_16x16x32_bf16(ah, bl8, acc[fc], 0, 0, 0);
        acc[fc] = __builtin_amdgcn_mfma_f32_16x16x32_bf16(ah, bh, acc[fc], 0, 0, 0);
      }
    }
  }
  #pragma unroll
  for (int fc = 0; fc < 8; ++fc) {
    int col = fc * 16 + (l & 15);
    #pragma unroll
    for (int i = 0; i < 4; ++i) {
      int lr = crow + i;
      zb[(rowBase + lr) * 128 + col] = acc[fc][i];
    }
  }
}

// ---------------------------------------------------------------------------
// cls: o1 = relu([xnew_lo|xnew_hi]@Wcl1+b1); o2 = relu(o1@Wcl2+b2);
//      out = o2@Wcl3 + bcl3 (N=2, shfl-reduced).
// ---------------------------------------------------------------------------
__global__ __launch_bounds__(256) void cls_kernel(
    const float* __restrict__ xnew,
    const ushort* __restrict__ W1h, const ushort* __restrict__ W1l,
    const float* __restrict__ b1,
    const ushort* __restrict__ W2h, const ushort* __restrict__ W2l,
    const float* __restrict__ b2,
    const float* __restrict__ Wcl3, const float* __restrict__ bcl3,
    float* __restrict__ out)
{
  __shared__ __align__(16) char O1h[16384], O1l[16384];
  __shared__ __align__(16) char AhB[8192], AlB[8192];
  __shared__ __align__(16) char BhB[16384], BlB[16384];
  const int tid = threadIdx.x;
  const int w = tid >> 6, l = tid & 63;
  const long rowBase = (long)blockIdx.x * 64;
  const int ar = w * 16 + (l & 15);
  const int crow = w * 16 + ((l >> 4) << 2);

  f32x4 acc[8];
  #pragma unroll
  for (int fc = 0; fc < 8; ++fc) acc[fc] = (f32x4){0.f, 0.f, 0.f, 0.f};
  for (int k0 = 0; k0 < 256; k0 += 64) {
    const float* Ab = (k0 < 128) ? xnew : (xnew + (long)B2 * 128);
    const int kc = k0 & 127;
    #pragma unroll
    for (int q = 0; q < 4; ++q) {
      int lin = tid + 256 * q;
      int r = lin >> 4, k4 = (lin & 15) << 2;
      float4 v = *(const float4*)&Ab[(rowBase + r) * 128 + kc + k4];
      ushort4 h4, l4;
      h4.x = f2bf(v.x); l4.x = f2bf(v.x - bf2f(h4.x));
      h4.y = f2bf(v.y); l4.y = f2bf(v.y - bf2f(h4.y));
      h4.z = f2bf(v.z); l4.z = f2bf(v.z - bf2f(h4.z));
      h4.w = f2bf(v.w); l4.w = f2bf(v.w - bf2f(h4.w));
      *(ushort4*)(AhB + swz128(r, k4 * 2)) = h4;
      *(ushort4*)(AlB + swz128(r, k4 * 2)) = l4;
    }
    #pragma unroll
    for (int q = 0; q < 4; ++q) {
      int lin = tid + 256 * q;
      int n = lin >> 3, k8 = (lin & 7) << 3;
      *(uint4*)(BhB + swz128(n, k8 * 2)) = *(const uint4*)&W1h[(long)n * 256 + k0 + k8];
      *(uint4*)(BlB + swz128(n, k8 * 2)) = *(const uint4*)&W1l[(long)n * 256 + k0 + k8];
    }
    __syncthreads();
    #pragma unroll
    for (int ks = 0; ks < 2; ++ks) {
      const int ko = ks * 32 + (l >> 4) * 8;
      short8 ah  = *(const short8*)(AhB + swz128(ar, ko * 2));
      short8 al8 = *(const short8*)(AlB + swz128(ar, ko * 2));
      #pragma unroll
      for (int fc = 0; fc < 8; ++fc) {
        const int c = fc * 16 + (l & 15);
        short8 bh  = *(const short8*)(BhB + swz128(c, ko * 2));
        short8 bl8 = *(const short8*)(BlB + swz128(c, ko * 2));
        acc[fc] = __builtin_amdgcn_mfma_f32_16x16x32_bf16(al8, bh, acc[fc], 0, 0, 0);
        acc[fc] = __builtin_amdgcn_mfma_f32_16x16x32_bf16(ah, bl8, acc[fc], 0, 0, 0);
        acc[fc] = __builtin_amdgcn_mfma_f32_16x16x32_bf16(ah, bh, acc[fc], 0, 0, 0);
      }
    }
    __syncthreads();
  }
  #pragma unroll
  for (int fc = 0; fc < 8; ++fc) {
    int col = fc * 16 + (l & 15);
    float bv = b1[col];
    #pragma unroll
    for (int i = 0; i < 4; ++i) {
      int lr = crow + i;
      float v = fmaxf(acc[fc][i] + bv, 0.f);
      ushort h = f2bf(v);
      *(ushort*)(O1h + swz256(lr, col * 2)) = h;
      *(ushort*)(O1l + swz256(lr, col * 2)) = f2bf(v - bf2f(h));
    }
  }

  #pragma unroll
  for (int fc = 0; fc < 8; ++fc) acc[fc] = (f32x4){0.f, 0.f, 0.f, 0.f};
  for (int k0 = 0; k0 < 128; k0 += 64) {
    __syncthreads();
    #pragma unroll
    for (int q = 0; q < 4; ++q) {
      int lin = tid + 256 * q;
      int n = lin >> 3, k8 = (lin & 7) << 3;
      *(uint4*)(BhB + swz128(n, k8 * 2)) = *(const uint4*)&W2h[n * 128 + k0 + k8];
      *(uint4*)(BlB + swz128(n, k8 * 2)) = *(const uint4*)&W2l[n * 128 + k0 + k8];
    }
    __syncthreads();
    #pragma unroll
    for (int ks = 0; ks < 2; ++ks) {
      const int ko = ks * 32 + (l >> 4) * 8;
      short8 ah  = *(const short8*)(O1h + swz256(ar, (k0 + ko) * 2));
      short8 al8 = *(const short8*)(O1l + swz256(ar, (k0 + ko) * 2));
      #pragma unroll
      for (int fc = 0; fc < 8; ++fc) {
        const int c = fc * 16 + (l & 15);
        short8 bh  = *(const short8*)(BhB + swz128(c, ko * 2));
        short8 bl8 = *(const short8*)(BlB + swz128(c, ko * 2));
        acc[fc] = __builtin_amdgcn_mfma_f32_16x16x32_bf16(al8, bh, acc[fc], 0, 0, 0);
        acc[fc] = __builtin_amdgcn_mfma_f32_16x16x32_bf16(ah, bl8, acc[fc], 0, 0, 0);
        acc[fc] = __builtin_amdgcn_mfma_f32_16x16x32_bf16(ah, bh, acc[fc], 0, 0, 0);
      }
    }
  }

  float p0[4] = {0.f, 0.f, 0.f, 0.f}, p1[4] = {0.f, 0.f, 0.f, 0.f};
  #pragma unroll
  for (int fc = 0; fc < 8; ++fc) {
    int col = fc * 16 + (l & 15);
    float bv = b2[col];
    float w0 = Wcl3[col * 2], w1 = Wcl3[col * 2 + 1];
    #pragma unroll
    for (int i = 0; i < 4; ++i) {
      float v = fmaxf(acc[fc][i] + bv, 0.f);
      p0[i] = fmaf(v, w0, p0[i]);
      p1[i] = fmaf(v, w1, p1[i]);
    }
  }
  #pragma unroll
  for (int i = 0; i < 4; ++i) {
    #pragma unroll
    for (int m = 1; m < 16; m <<= 1) {
      p0[i] += __shfl_xor(p0[i], m);
      p1[i] += __shfl_xor(p1[i], m);
    }
    if ((l & 15) == 0) {
      long row = rowBase + crow + i;
      out[row * 2 + 0] = p0[i] + bcl3[0];
      out[row * 2 + 1] = p1[i] + bcl3[1];
    }
  }
}

// ---------------------------------------------------------------------------
// zfold v3: same structure/grid as validated round-8 version, but acc merge
// buffers ALIAS the dead B-tiles after the last MFMA -> LDS 75KB, 2 blocks/CU.
// ---------------------------------------------------------------------------
__global__ __launch_bounds__(256, 2) void zfold_mfma_kernel(
    const float* __restrict__ xp,
    const ushort* __restrict__ We2h, const ushort* __restrict__ We2l,
    const float* __restrict__ interhb, const float* __restrict__ ia1,
    const float* __restrict__ ia2, const float* __restrict__ We1,
    const float* __restrict__ be1,
    float* __restrict__ aggA, float* __restrict__ aggB)
{
  __shared__ __align__(16) char poolz[76800];
  ushort* AhP = (ushort*)poolz;                 // [2][4608]  [0,18432)
  ushort* AlP = (ushort*)(poolz + 18432);       // [2][4608]  [18432,36864)
  ushort* Bh  = (ushort*)(poolz + 36864);       // [9216]     [36864,55296)
  ushort* Bl  = (ushort*)(poolz + 55296);       // [9216]     [55296,73728)
  float (*ehs)[32][8] = (float(*)[32][8])(poolz + 73728);  // [3][32][8] 3072B
  float* accAs = (float*)(poolz + 36864);       // alias B region (post-MFMA)
  float* accBs = (float*)(poolz + 53248);

  const int tid = threadIdx.x;
  const int w = tid >> 6, l = tid & 63;
  const int rg = blockIdx.x >> 2, kq = blockIdx.x & 3;
  const int i0 = rg * 32;

  for (int t = tid; t < 2048; t += 256) {
    int r = t >> 5, k4 = (t & 31) << 2;
    int gr = (r < 32) ? (i0 + r) : (B2 + i0 + r - 32);
    float4 v = *(const float4*)&xp[(long)gr * 128 + k4];
    int ch = k4 >> 6, ko = k4 & 63;
    ushort4 h4, l4;
    h4.x = f2bf(v.x); l4.x = f2bf(v.x - bf2f(h4.x));
    h4.y = f2bf(v.y); l4.y = f2bf(v.y - bf2f(h4.y));
    h4.z = f2bf(v.z); l4.z = f2bf(v.z - bf2f(h4.z));
    h4.w = f2bf(v.w); l4.w = f2bf(v.w - bf2f(h4.w));
    *(ushort4*)&AhP[ch * 4608 + r * 72 + ko] = h4;
    *(ushort4*)&AlP[ch * 4608 + r * 72 + ko] = l4;
  }
  for (int t = tid; t < 768; t += 256) {
    int grp = t >> 8, rem = t & 255;
    int mm = rem >> 3, kk = rem & 7;
    int k = kq * 8 + kk;
    float u = (grp == 0) ? interhb[i0 + mm] : (grp == 1) ? ia1[i0 + mm] : ia2[i0 + mm];
    ehs[grp][mm][kk] = fmaxf(fmaf(u, We1[k], be1[k]), 0.f);
  }

  float foldA[8][4] = {{0.f}}, foldB[8][4] = {{0.f}};
  const int ar = w * 16 + (l & 15);

  for (int kk = 0; kk < 8; ++kk) {
    const int k = kq * 8 + kk;
    f32x4 acc[8];
    #pragma unroll
    for (int fc = 0; fc < 8; ++fc) acc[fc] = (f32x4){0.f, 0.f, 0.f, 0.f};
    for (int ch = 0; ch < 2; ++ch) {
      __syncthreads();
      #pragma unroll
      for (int q = 0; q < 4; ++q) {
        int lin = tid + 256 * q;
        int n = lin >> 3, k8 = (lin & 7) << 3;
        *(uint4*)&Bh[n * 72 + k8] = *(const uint4*)&We2h[k * 16384 + n * 128 + ch * 64 + k8];
        *(uint4*)&Bl[n * 72 + k8] = *(const uint4*)&We2l[k * 16384 + n * 128 + ch * 64 + k8];
      }
      __syncthreads();
      #pragma unroll
      for (int ks = 0; ks < 2; ++ks) {
        const int ko = ks * 32 + (l >> 4) * 8;
        short8 ah  = *(const short8*)&AhP[ch * 4608 + ar * 72 + ko];
        short8 al8 = *(const short8*)&AlP[ch * 4608 + ar * 72 + ko];
        #pragma unroll
        for (int fc = 0; fc < 8; ++fc) {
          const int c = fc * 16 + (l & 15);
          short8 bh  = *(const short8*)&Bh[c * 72 + ko];
          short8 bl8 = *(const short8*)&Bl[c * 72 + ko];
          acc[fc] = __builtin_amdgcn_mfma_f32_16x16x32_bf16(al8, bh, acc[fc], 0, 0, 0);
          acc[fc] = __builtin_amdgcn_mfma_f32_16x16x32_bf16(ah, bl8, acc[fc], 0, 0, 0);
          acc[fc] = __builtin_amdgcn_mfma_f32_16x16x32_bf16(ah, bh, acc[fc], 0, 0, 0);
        }
      }
    }
    #pragma unroll
    for (int i = 0; i < 4; ++i) {
      int lr = w * 16 + ((l >> 4) << 2) + i;
      int m = lr & 31, up = lr >> 5;
      float eA = up ? ehs[0][m][kk] : ehs[1][m][kk];
      float eB = up ? ehs[2][m][kk] : ehs[0][m][kk];
      #pragma unroll
      for (int fc = 0; fc < 8; ++fc) {
        foldA[fc][i] = fmaf(eA, acc[fc][i], foldA[fc][i]);
        foldB[fc][i] = fmaf(eB, acc[fc][i], foldB[fc][i]);
      }
    }
  }
  __syncthreads();   // all MFMA reads of B done -> B region reusable
  for (int t = tid; t < 8192; t += 256) ((float*)(poolz + 36864))[t] = 0.f;
  __syncthreads();
  #pragma unroll
  for (int i = 0; i < 4; ++i) {
    int lr = w * 16 + ((l >> 4) << 2) + i;
    int m = lr & 31;
    #pragma unroll
    for (int fc = 0; fc < 8; ++fc) {
      int c = fc * 16 + (l & 15);
      atomicAdd(&accAs[m * 128 + c], foldA[fc][i]);
      atomicAdd(&accBs[m * 128 + c], foldB[fc][i]);
    }
  }
  __syncthreads();
  for (int t = tid; t < 4096; t += 256) {
    int mm = t >> 7, c = t & 127;
    atomicAdd(&aggA[(long)(i0 + mm) * 128 + c], accAs[t]);
    atomicAdd(&aggB[(long)(i0 + mm) * 128 + c], accBs[t]);
  }
}

// ---------------------------------------------------------------------------
// FULLY-FUSED ALL-MFMA GraphConv + inline adjacency build (validated r18).
// ---------------------------------------------------------------------------
__global__ __launch_bounds__(512, 4) void gconv_kernel(
    const float* __restrict__ h1, const float* __restrict__ h2,
    const int* __restrict__ src1, const int* __restrict__ dst1,
    const int* __restrict__ src2, const int* __restrict__ dst2,
    const float* __restrict__ bg1,
    const ushort* __restrict__ W1h, const ushort* __restrict__ W1l,
    const ushort* __restrict__ W2h, const ushort* __restrict__ W2l,
    const float* __restrict__ bias2, const float* __restrict__ s1x,
    float* __restrict__ xcat)
{
  __shared__ __align__(16) char pool[66560];
  char* AhB = pool;
  char* AlB = pool + 16384;
  char* BhB = pool + 32768;
  char* BlB = pool + 49152;
  char* A2h = pool;
  char* A2l = pool + 8192;
  char* Byh = pool + 32768;
  char* Byl = pool + 49152;
  float* cs = (float*)(pool + 65536);
  float* cntS = (float*)(pool + 16384);
  float* rsIS = (float*)(pool + 24576);
  float* rsOS = (float*)(pool + 24832);

  const int tid = threadIdx.x;
  const int p = blockIdx.x;
  const int g = p >> 10;
  const int mloc = (p & 1023) * 2;
  const float* hsrc = g ? h2 : h1;
  if (tid < 256) cs[tid] = 0.f;

  const int w8 = tid >> 6, l = tid & 63;
  const int rw = w8 & 3;
  const int ch2 = w8 >> 2;
  const int ar = rw * 16 + (l & 15);
  const int crow = rw * 16 + ((l >> 4) << 2);

  #pragma unroll
  for (int q = 0; q < 4; ++q) {
    int lin = tid + 512 * q;
    int r = lin >> 5, k4 = (lin & 31) << 2;
    float4 v = make_float4(0.f, 0.f, 0.f, 0.f);
    if (r < 60) {
      const float* Ar = &hsrc[(long)(mloc * 30 + r) * 74];
      if (k4 + 4 <= 74) {
        float2 a = *(const float2*)&Ar[k4];
        float2 b = *(const float2*)&Ar[k4 + 2];
        v = make_float4(a.x, a.y, b.x, b.y);
      } else if (k4 + 2 <= 74) {
        float2 a = *(const float2*)&Ar[k4];
        v.x = a.x; v.y = a.y;
      }
    }
    ushort4 h4, l4;
    h4.x = f2bf(v.x); l4.x = f2bf(v.x - bf2f(h4.x));
    h4.y = f2bf(v.y); l4.y = f2bf(v.y - bf2f(h4.y));
    h4.z = f2bf(v.z); l4.z = f2bf(v.z - bf2f(h4.z));
    h4.w = f2bf(v.w); l4.w = f2bf(v.w - bf2f(h4.w));
    *(ushort4*)(AhB + swz256(r, k4 * 2)) = h4;
    *(ushort4*)(AlB + swz256(r, k4 * 2)) = l4;
  }
  __syncthreads();

  f32x4 acc[4];
  #pragma unroll
  for (int fc = 0; fc < 4; ++fc) acc[fc] = (f32x4){0.f, 0.f, 0.f, 0.f};
  for (int k0 = 0; k0 < 128; k0 += 64) {
    #pragma unroll
    for (int q = 0; q < 2; ++q) {
      int lin = tid + 512 * q;
      int n = lin >> 3, k8 = (lin & 7) << 3;
      *(uint4*)(BhB + swz128(n, k8 * 2)) = *(const uint4*)&W1h[n * 128 + k0 + k8];
      *(uint4*)(BlB + swz128(n, k8 * 2)) = *(const uint4*)&W1l[n * 128 + k0 + k8];
    }
    __syncthreads();
    #pragma unroll
    for (int ks = 0; ks < 2; ++ks) {
      const int ko = ks * 32 + (l >> 4) * 8;
      short8 ah  = *(const short8*)(AhB + swz256(ar, (k0 + ko) * 2));
      short8 al8 = *(const short8*)(AlB + swz256(ar, (k0 + ko) * 2));
      #pragma unroll
      for (int fc = 0; fc < 4; ++fc) {
        const int c = ch2 * 64 + fc * 16 + (l & 15);
        short8 bh  = *(const short8*)(BhB + swz128(c, ko * 2));
        short8 bl8 = *(const short8*)(BlB + swz128(c, ko * 2));
        acc[fc] = __builtin_amdgcn_mfma_f32_16x16x32_bf16(al8, bh, acc[fc], 0, 0, 0);
        acc[fc] = __builtin_amdgcn_mfma_f32_16x16x32_bf16(ah, bl8, acc[fc], 0, 0, 0);
        acc[fc] = __builtin_amdgcn_mfma_f32_16x16x32_bf16(ah, bh, acc[fc], 0, 0, 0);
      }
    }
    __syncthreads();
  }

  #pragma unroll
  for (int fc = 0; fc < 4; ++fc) {
    int n = ch2 * 64 + fc * 16 + (l & 15);
    ushort4 h4, l4;
    h4.x = f2bf(acc[fc][0]); l4.x = f2bf(acc[fc][0] - bf2f(h4.x));
    h4.y = f2bf(acc[fc][1]); l4.y = f2bf(acc[fc][1] - bf2f(h4.y));
    h4.z = f2bf(acc[fc][2]); l4.z = f2bf(acc[fc][2] - bf2f(h4.z));
    h4.w = f2bf(acc[fc][3]); l4.w = f2bf(acc[fc][3] - bf2f(h4.w));
    *(ushort4*)(Byh + swz128(n, crow * 2)) = h4;
    *(ushort4*)(Byl + swz128(n, crow * 2)) = l4;
  }
  for (int t = tid; t < 2176; t += 512) ((float*)(pool + 16384))[t] = 0.f;
  __syncthreads();

  if (tid < 2 * EPM) {
    int mol = tid / EPM, e = tid - mol * EPM;
    const int* srcp = g ? src2 : src1;
    const int* dstp = g ? dst2 : dst1;
    int m = mloc + mol;
    int s = srcp[m * EPM + e] - m * NPM;
    int d = dstp[m * EPM + e] - m * NPM;
    atomicAdd(&cntS[mol * 990 + d * 33 + s], 1.0f);
  }
  __syncthreads();

  if (tid < 60) {
    int mol = tid / 30, r = tid - mol * 30;
    float s = 0.f;
    for (int k = 0; k < 30; ++k) s += cntS[mol * 990 + r * 33 + k];
    rsIS[mol * 32 + r] = rsqrtf(fmaxf(s, 1.f));
  } else if (tid >= 64 && tid < 124) {
    int t2 = tid - 64;
    int mol = t2 / 30, sc = t2 - mol * 30;
    float s = 0.f;
    for (int d = 0; d < 30; ++d) s += cntS[mol * 990 + d * 33 + sc];
    rsOS[mol * 32 + sc] = rsqrtf(fmaxf(s, 1.f));
  }
  __syncthreads();

  for (int t = tid; t < 4096; t += 512) {
    int row = t >> 6, k = t & 63;
    float v = 0.f;
    if (row < 30) {
      if (k < 30) v = cntS[row * 33 + k] * rsIS[row] * rsOS[k];
    } else if (row < 60) {
      if (k >= 30 && k < 60)
        v = cntS[990 + (row - 30) * 33 + (k - 30)] * rsIS[32 + row - 30] * rsOS[32 + k - 30];
    }
    ushort h = f2bf(v);
    *(ushort*)(A2h + swz128(row, k * 2)) = h;
    *(ushort*)(A2l + swz128(row, k * 2)) = f2bf(v - bf2f(h));
  }
  __syncthreads();

  f32x4 acc2[4];
  #pragma unroll
  for (int fc = 0; fc < 4; ++fc) acc2[fc] = (f32x4){0.f, 0.f, 0.f, 0.f};
  #pragma unroll
  for (int ks = 0; ks < 2; ++ks) {
    const int ko = ks * 32 + (l >> 4) * 8;
    short8 ah  = *(const short8*)(A2h + swz128(ar, ko * 2));
    short8 al8 = *(const short8*)(A2l + swz128(ar, ko * 2));
    #pragma unroll
    for (int fc = 0; fc < 4; ++fc) {
      const int c = ch2 * 64 + fc * 16 + (l & 15);
      short8 bh  = *(const short8*)(Byh + swz128(c, ko * 2));
      short8 bl8 = *(const short8*)(Byl + swz128(c, ko * 2));
      acc2[fc] = __builtin_amdgcn_mfma_f32_16x16x32_bf16(al8, bh, acc2[fc], 0, 0, 0);
      acc2[fc] = __builtin_amdgcn_mfma_f32_16x16x32_bf16(ah, bl8, acc2[fc], 0, 0, 0);
      acc2[fc] = __builtin_amdgcn_mfma_f32_16x16x32_bf16(ah, bh, acc2[fc], 0, 0, 0);
    }
  }
  __syncthreads();

  #pragma unroll
  for (int fc = 0; fc < 4; ++fc) {
    int n = ch2 * 64 + fc * 16 + (l & 15);
    float bv = bg1[n];
    float t0 = fmaxf(acc2[fc][0] + bv, 0.f);
    float t1v = fmaxf(acc2[fc][1] + bv, 0.f);
    float t2v = fmaxf(acc2[fc][2] + bv, 0.f);
    float t3 = fmaxf(acc2[fc][3] + bv, 0.f);
    ushort4 h4, l4;
    h4.x = f2bf(t0); l4.x = f2bf(t0 - bf2f(h4.x));
    h4.y = f2bf(t1v); l4.y = f2bf(t1v - bf2f(h4.y));
    h4.z = f2bf(t2v); l4.z = f2bf(t2v - bf2f(h4.z));
    h4.w = f2bf(t3); l4.w = f2bf(t3 - bf2f(h4.w));
    *(ushort4*)(Byh + swz128(n, crow * 2)) = h4;
    *(ushort4*)(Byl + swz128(n, crow * 2)) = l4;
  }
  __syncthreads();

  #pragma unroll
  for (int fc = 0; fc < 4; ++fc) acc2[fc] = (f32x4){0.f, 0.f, 0.f, 0.f};
  #pragma unroll
  for (int ks = 0; ks < 2; ++ks) {
    const int ko = ks * 32 + (l >> 4) * 8;
    short8 ah  = *(const short8*)(A2h + swz128(ar, ko * 2));
    short8 al8 = *(const short8*)(A2l + swz128(ar, ko * 2));
    #pragma unroll
    for (int fc = 0; fc < 4; ++fc) {
      const int c = ch2 * 64 + fc * 16 + (l & 15);
      short8 bh  = *(const short8*)(Byh + swz128(c, ko * 2));
      short8 bl8 = *(const short8*)(Byl + swz128(c, ko * 2));
      acc2[fc] = __builtin_amdgcn_mfma_f32_16x16x32_bf16(al8, bh, acc2[fc], 0, 0, 0);
      acc2[fc] = __builtin_amdgcn_mfma_f32_16x16x32_bf16(ah, bl8, acc2[fc], 0, 0, 0);
      acc2[fc] = __builtin_amdgcn_mfma_f32_16x16x32_bf16(ah, bh, acc2[fc], 0, 0, 0);
    }
  }
  __syncthreads();

  #pragma unroll
  for (int fc = 0; fc < 4; ++fc) {
    int n = ch2 * 64 + fc * 16 + (l & 15);
    #pragma unroll
    for (int i = 0; i < 4; ++i) {
      int r = crow + i;
      ushort h = f2bf(acc2[fc][i]);
      *(ushort*)(AhB + swz256(r, n * 2)) = h;
      *(ushort*)(AlB + swz256(r, n * 2)) = f2bf(acc2[fc][i] - bf2f(h));
    }
  }

  #pragma unroll
  for (int fc = 0; fc < 4; ++fc) acc[fc] = (f32x4){0.f, 0.f, 0.f, 0.f};
  for (int k0 = 0; k0 < 128; k0 += 64) {
    __syncthreads();
    #pragma unroll
    for (int q = 0; q < 2; ++q) {
      int lin = tid + 512 * q;
      int n = lin >> 3, k8 = (lin & 7) << 3;
      *(uint4*)(BhB + swz128(n, k8 * 2)) = *(const uint4*)&W2h[n * 128 + k0 + k8];
      *(uint4*)(BlB + swz128(n, k8 * 2)) = *(const uint4*)&W2l[n * 128 + k0 + k8];
    }
    __syncthreads();
    #pragma unroll
    for (int ks = 0; ks < 2; ++ks) {
      const int ko = ks * 32 + (l >> 4) * 8;
      short8 ah  = *(const short8*)(AhB + swz256(ar, (k0 + ko) * 2));
      short8 al8 = *(const short8*)(AlB + swz256(ar, (k0 + ko) * 2));
      #pragma unroll
      for (int fc = 0; fc < 4; ++fc) {
        const int c = ch2 * 64 + fc * 16 + (l & 15);
        short8 bh  = *(const short8*)(BhB + swz128(c, ko * 2));
        short8 bl8 = *(const short8*)(BlB + swz128(c, ko * 2));
        acc[fc] = __builtin_amdgcn_mfma_f32_16x16x32_bf16(al8, bh, acc[fc], 0, 0, 0);
        acc[fc] = __builtin_amdgcn_mfma_f32_16x16x32_bf16(ah, bl8, acc[fc], 0, 0, 0);
        acc[fc] = __builtin_amdgcn_mfma_f32_16x16x32_bf16(ah, bh, acc[fc], 0, 0, 0);
      }
    }
  }
  __syncthreads();

  #pragma unroll
  for (int fc = 0; fc < 4; ++fc) {
    int col = ch2 * 64 + fc * 16 + (l & 15);
    float bv = bias2[col];
    float s0 = 0.f, s1 = 0.f;
    #pragma unroll
    for (int i = 0; i < 4; ++i) {
      int lr = crow + i;
      if (lr < 60) {
        float v = fmaxf(acc[fc][i] + bv, 0.f);
        if (lr < NPM) s0 += v; else s1 += v;
      }
    }
    s0 += __shfl_down(s0, 32); s0 += __shfl_down(s0, 16);
    s1 += __shfl_down(s1, 32); s1 += __shfl_down(s1, 16);
    if ((l >> 4) == 0) {
      atomicAdd(&cs[col], s0);
      atomicAdd(&cs[128 + col], s1);
    }
  }
  __syncthreads();
  if (tid < 256) {
    int moll = tid >> 7, c = tid & 127;
    int gm = p * 2 + moll;
    int gg = gm >> 11, mm = gm & 2047;
    float sf = gg ? (1.f - s1x[mm]) : s1x[mm];
    xcat[(long)gm * 128 + c] = cs[moll * 128 + c] * (1.f / 30.f) * sf;
  }
}

// ---------------------------------------------------------------------------
extern "C" void kernel_launch(void* const* d_in, const int* in_sizes, int n_in,
                              void* d_out, int out_size, void* d_ws, size_t ws_size,
                              hipStream_t stream)
{
  const float* h1   = (const float*)d_in[0];
  const float* h2   = (const float*)d_in[1];
  const float* s1x  = (const float*)d_in[2];
  const float* ihb  = (const float*)d_in[3];
  const float* ia1  = (const float*)d_in[4];
  const float* ia2  = (const float*)d_in[5];
  const float* Wg1  = (const float*)d_in[6];
  const float* bg1  = (const float*)d_in[7];
  const float* Wg2  = (const float*)d_in[8];
  const float* bg2  = (const float*)d_in[9];
  const float* Wp   = (const float*)d_in[10];
  const float* bp   = (const float*)d_in[11];
  const float* We1  = (const float*)d_in[12];
  const float* be1  = (const float*)d_in[13];
  const float* We2  = (const float*)d_in[14];
  const float* be2  = (const float*)d_in[15];
  const float* bnn  = (const float*)d_in[16];
  const float* Wih  = (const float*)d_in[17];
  const float* bih  = (const float*)d_in[18];
  const float* Whh  = (const float*)d_in[19];
  const float* bhh  = (const float*)d_in[20];
  const float* Wcl1 = (const float*)d_in[21];
  const float* bcl1 = (const float*)d_in[22];
  const float* Wcl2 = (const float*)d_in[23];
  const float* bcl2 = (const float*)d_in[24];
  const float* Wcl3 = (const float*)d_in[25];
  const float* bcl3 = (const float*)d_in[26];
  const int*   src1 = (const int*)d_in[27];
  const int*   dst1 = (const int*)d_in[28];
  const int*   src2 = (const int*)d_in[29];
  const int*   dst2 = (const int*)d_in[30];
  float* out = (float*)d_out;
  float* ws  = (float*)d_ws;

  float* dwn  = ws + 35389440;

  float* xcat = dwn;
  float* xp   = dwn + 524288;
  float* zb   = dwn + 1048576;
  float* aggA = dwn + 1572864;
  float* aggB = dwn + 1835008;
  float* xnew = dwn + 2097152;

  ushort* wt     = (ushort*)(dwn + 6815744);
  ushort* WpTh   = wt;               ushort* WpTl   = wt + 16384;
  ushort* be2Th  = wt + 32768;       ushort* be2Tl  = wt + 49152;
  ushort* WihTh  = wt + 65536;       ushort* WihTl  = wt + 114688;
  ushort* WhhTh  = wt + 163840;      ushort* WhhTl  = wt + 212992;
  ushort* Wcl1Th = wt + 262144;      ushort* Wcl1Tl = wt + 294912;
  ushort* Wcl2Th = wt + 327680;      ushort* Wcl2Tl = wt + 344064;
  ushort* Wg1Th  = wt + 360448;      ushort* Wg1Tl  = wt + 376832;
  ushort* Wg2Th  = wt + 393216;      ushort* Wg2Tl  = wt + 409600;
  ushort* We2h   = wt + 425984;      ushort* We2l   = wt + 950272;

  // ---- fused weight prep (8 weights in one launch) ----
  PrepDescs pd;
  const float* Ws_[8]  = {Wp, be2, Wih, Whh, Wcl1, Wcl2, Wg1, Wg2};
  ushort* his[8]       = {WpTh, be2Th, WihTh, WhhTh, Wcl1Th, Wcl2Th, Wg1Th, Wg2Th};
  ushort* los[8]       = {WpTl, be2Tl, WihTl, WhhTl, Wcl1Tl, Wcl2Tl, Wg1Tl, Wg2Tl};
  int kr[8]   = {128, 128, 128, 128, 256, 128, 74, 128};
  int kp[8]   = {128, 128, 128, 128, 256, 128, 128, 128};
  int nn[8]   = {128, 128, 384, 384, 128, 128, 128, 128};
  int acc_blk = 0;
  for (int i = 0; i < 8; ++i) {
    pd.W[i] = Ws_[i]; pd.hi[i] = his[i]; pd.lo[i] = los[i];
    pd.Kreal[i] = kr[i]; pd.Kpad[i] = kp[i]; pd.N[i] = nn[i];
    pd.blk0[i] = acc_blk;
    acc_blk += (nn[i] * (kp[i] >> 3) + 255) / 256;
  }
  pd.blk0[8] = acc_blk;
  prep_all_kernel<<<acc_blk, 256, 0, stream>>>(pd);
  prep_we2_kernel<<<256, 256, 0, stream>>>(We2, We2h, We2l);

  // ---- fully-fused GraphConv (adjacency built in-block) ----
  gconv_kernel<<<2048, 512, 0, stream>>>(h1, h2, src1, dst1, src2, dst2,
                                         bg1, Wg1Th, Wg1Tl, Wg2Th, Wg2Tl,
                                         bg2, s1x, xcat);

  // ---- solvent-system MPNN + fused GRU + classifier ----
  xpzb_kernel<<<64, 256, 0, stream>>>(xcat, WpTh, WpTl, bp, be2Th, be2Tl, xp, zb);
  hipMemsetAsync(aggA, 0, 2 * 262144 * sizeof(float), stream);
  zfold_mfma_kernel<<<256, 256, 0, stream>>>(xp, We2h, We2l, ihb, ia1, ia2,
                                             We1, be1, aggA, aggB);
  grufuse_kernel<<<512, 256, 0, stream>>>(aggA, aggB, zb, bnn, xp,
                                          WihTh, WihTl, bih, WhhTh, WhhTl, bhh,
                                          xnew);
  cls_kernel<<<32, 256, 0, stream>>>(xnew, Wcl1Th, Wcl1Tl, bcl1,
                                     Wcl2Th, Wcl2Tl, bcl2, Wcl3, bcl3, out);
}

// Round 20
// 169.426 us; speedup vs baseline: 1.0367x; 1.0367x over previous
//
#include <hip/hip_runtime.h>
#include <hip/hip_bf16.h>
#include <math.h>

#define B2    2048
#define NPM   30
#define EPM   120

typedef __attribute__((ext_vector_type(8))) short short8;
typedef __attribute__((ext_vector_type(4))) float f32x4;

__device__ __forceinline__ ushort f2bf(float x) {
  unsigned u = __float_as_uint(x);
  return (ushort)((u + 0x7FFFu + ((u >> 16) & 1u)) >> 16);
}
__device__ __forceinline__ float bf2f(ushort h) {
  return __uint_as_float(((unsigned)h) << 16);
}

// swizzled byte offsets: 128B rows (per-chunk tiles) and 256B rows (full-K A)
__device__ __forceinline__ int swz128(int r, int kb) { return r * 128 + (kb ^ ((r & 7) << 4)); }
__device__ __forceinline__ int swz256(int r, int kb) { return r * 256 + (kb ^ ((r & 15) << 4)); }

// ---------------------------------------------------------------------------
// prep_all: 8 weight preps in one launch. W[Kreal][N] -> bf16 split [N][Kpad].
// ---------------------------------------------------------------------------
struct PrepDescs {
  const float* W[8];
  ushort* hi[8];
  ushort* lo[8];
  int Kreal[8], Kpad[8], N[8];
  int blk0[9];
};

__global__ __launch_bounds__(256) void prep_all_kernel(PrepDescs d)
{
  int b = blockIdx.x;
  int di = 0;
  #pragma unroll
  for (int j = 1; j < 8; ++j) if (b >= d.blk0[j]) di = j;
  int idx = (b - d.blk0[di]) * 256 + threadIdx.x;
  int Kp8 = d.Kpad[di] >> 3;
  int tot = d.N[di] * Kp8;
  if (idx >= tot) return;
  int n = idx / Kp8;
  int k8 = (idx - n * Kp8) << 3;
  const float* W = d.W[di];
  ushort* hi = d.hi[di];
  ushort* lo = d.lo[di];
  int Kreal = d.Kreal[di], Kpad = d.Kpad[di], N = d.N[di];
  #pragma unroll
  for (int j = 0; j < 8; ++j) {
    int k = k8 + j;
    float x = (k < Kreal) ? W[(long)k * N + n] : 0.f;
    ushort h = f2bf(x);
    hi[(long)n * Kpad + k] = h;
    lo[(long)n * Kpad + k] = f2bf(x - bf2f(h));
  }
}

// We2[32][128][128] -> per-k transposed bf16 split hi/lo[k][n][d]
__global__ __launch_bounds__(256) void prep_we2_kernel(
    const float* __restrict__ We2, ushort* __restrict__ hi, ushort* __restrict__ lo)
{
  int idx = blockIdx.x * 256 + threadIdx.x;
  int k = idx >> 11;
  int rem = idx & 2047;
  int n = rem >> 4;
  int d8 = (rem & 15) << 3;
  #pragma unroll
  for (int j = 0; j < 8; ++j) {
    int d = d8 + j;
    float x = We2[k * 16384 + d * 128 + n];
    ushort h = f2bf(x);
    hi[k * 16384 + n * 128 + d] = h;
    lo[k * 16384 + n * 128 + d] = f2bf(x - bf2f(h));
  }
}

// ---------------------------------------------------------------------------
// grufuse v2 (validated round 15): 32x32 tiles, 512 blocks.
// ---------------------------------------------------------------------------
__global__ __launch_bounds__(256, 4) void grufuse_kernel(
    const float* __restrict__ aggA, const float* __restrict__ aggB,
    const float* __restrict__ zb, const float* __restrict__ bnn,
    const float* __restrict__ xp,
    const ushort* __restrict__ Wihh, const ushort* __restrict__ Wihl,
    const float* __restrict__ bih,
    const ushort* __restrict__ Whhh, const ushort* __restrict__ Whhl,
    const float* __restrict__ bhh,
    float* __restrict__ xnew)
{
  __shared__ __align__(16) char A1h[8192], A1l[8192];
  __shared__ __align__(16) char A2h[8192], A2l[8192];
  __shared__ __align__(16) char Bh[4096], Bl[4096];
  const int tid = threadIdx.x;
  const int w = tid >> 6, l = tid & 63;
  const int rt = blockIdx.x >> 2;
  const int qt = blockIdx.x & 3;
  const long rowBase = (long)rt * 32;
  const int rw = w & 1;
  const int cs = w >> 1;
  const int ar = rw * 16 + (l & 15);
  const int crow = rw * 16 + ((l >> 4) << 2);

  #pragma unroll
  for (int q = 0; q < 4; ++q) {
    int t = tid + 256 * q;
    int r = t >> 5, k4 = (t & 31) << 2;
    long gr = rowBase + r;
    long i = (gr < B2) ? gr : (gr - B2);
    float4 za = *(const float4*)&zb[i * 128 + k4];
    float4 zc = *(const float4*)&zb[(i + B2) * 128 + k4];
    float4 bn = *(const float4*)&bnn[k4];
    const float* ap = (gr < B2) ? &aggA[i * 128 + k4] : &aggB[i * 128 + k4];
    float4 ag = *(const float4*)ap;
    float4 xv;
    xv.x = fmaxf(ag.x + za.x + zc.x + bn.x, 0.f);
    xv.y = fmaxf(ag.y + za.y + zc.y + bn.y, 0.f);
    xv.z = fmaxf(ag.z + za.z + zc.z + bn.z, 0.f);
    xv.w = fmaxf(ag.w + za.w + zc.w + bn.w, 0.f);
    ushort4 h4, l4;
    h4.x = f2bf(xv.x); l4.x = f2bf(xv.x - bf2f(h4.x));
    h4.y = f2bf(xv.y); l4.y = f2bf(xv.y - bf2f(h4.y));
    h4.z = f2bf(xv.z); l4.z = f2bf(xv.z - bf2f(h4.z));
    h4.w = f2bf(xv.w); l4.w = f2bf(xv.w - bf2f(h4.w));
    *(ushort4*)(A1h + swz256(r, k4 * 2)) = h4;
    *(ushort4*)(A1l + swz256(r, k4 * 2)) = l4;
    float4 pv = *(const float4*)&xp[gr * 128 + k4];
    h4.x = f2bf(pv.x); l4.x = f2bf(pv.x - bf2f(h4.x));
    h4.y = f2bf(pv.y); l4.y = f2bf(pv.y - bf2f(h4.y));
    h4.z = f2bf(pv.z); l4.z = f2bf(pv.z - bf2f(h4.z));
    h4.w = f2bf(pv.w); l4.w = f2bf(pv.w - bf2f(h4.w));
    *(ushort4*)(A2h + swz256(r, k4 * 2)) = h4;
    *(ushort4*)(A2l + swz256(r, k4 * 2)) = l4;
  }
  __syncthreads();

  f32x4 rg = (f32x4){0,0,0,0}, zg = (f32x4){0,0,0,0};

  for (int gate = 0; gate < 3; ++gate) {
    f32x4 gi = (f32x4){0,0,0,0}, gh = (f32x4){0,0,0,0};
    for (int src = 0; src < 2; ++src) {
      const ushort* Wh = src ? Whhh : Wihh;
      const ushort* Wl = src ? Whhl : Wihl;
      const char* Ah = src ? A2h : A1h;
      const char* Al = src ? A2l : A1l;
      for (int k0 = 0; k0 < 128; k0 += 64) {
        __syncthreads();
        {
          int n = tid >> 3, k8 = (tid & 7) << 3;
          long wrow = (long)(gate * 128 + qt * 32 + n);
          *(uint4*)(Bh + swz128(n, k8 * 2)) = *(const uint4*)&Wh[wrow * 128 + k0 + k8];
          *(uint4*)(Bl + swz128(n, k8 * 2)) = *(const uint4*)&Wl[wrow * 128 + k0 + k8];
        }
        __syncthreads();
        f32x4 a = (src == 0) ? gi : gh;
        #pragma unroll
        for (int ks = 0; ks < 2; ++ks) {
          const int ko = ks * 32 + (l >> 4) * 8;
          short8 ah  = *(const short8*)(Ah + swz256(ar, (k0 + ko) * 2));
          short8 al8 = *(const short8*)(Al + swz256(ar, (k0 + ko) * 2));
          const int c = cs * 16 + (l & 15);
          short8 bh  = *(const short8*)(Bh + swz128(c, ko * 2));
          short8 bl8 = *(const short8*)(Bl + swz128(c, ko * 2));
          a = __builtin_amdgcn_mfma_f32_16x16x32_bf16(al8, bh, a, 0, 0, 0);
          a = __builtin_amdgcn_mfma_f32_16x16x32_bf16(ah, bl8, a, 0, 0, 0);
          a = __builtin_amdgcn_mfma_f32_16x16x32_bf16(ah, bh, a, 0, 0, 0);
        }
        if (src == 0) gi = a; else gh = a;
      }
    }
    int cg = qt * 32 + cs * 16 + (l & 15);
    float bi = bih[gate * 128 + cg], bh2 = bhh[gate * 128 + cg];
    #pragma unroll
    for (int i = 0; i < 4; ++i) {
      float a = gi[i] + bi;
      float b = gh[i] + bh2;
      if (gate == 0) {
        rg[i] = 1.f / (1.f + expf(-(a + b)));
      } else if (gate == 1) {
        zg[i] = 1.f / (1.f + expf(-(a + b)));
      } else {
        float ng = tanhf(a + rg[i] * b);
        long row = rowBase + crow + i;
        float h = xp[row * 128 + cg];
        xnew[row * 128 + cg] = (1.f - zg[i]) * ng + zg[i] * h;
      }
    }
  }
}

// ---------------------------------------------------------------------------
// xpzb v2: 32-row tiles, grid 128 (2 row-waves x 2 col-halves, fc=4).
// xp = relu(xcat@Wp+bp); zb = xp@be2 (xp kept in LDS).
// LDS 48KB -> 3 blocks/CU.
// ---------------------------------------------------------------------------
__global__ __launch_bounds__(256, 3) void xpzb_kernel(
    const float* __restrict__ xcat,
    const ushort* __restrict__ Wph, const ushort* __restrict__ Wpl,
    const float* __restrict__ bp,
    const ushort* __restrict__ be2h, const ushort* __restrict__ be2l,
    float* __restrict__ xp, float* __restrict__ zb)
{
  __shared__ __align__(16) char AhB[8192], AlB[8192];    // 32 rows x 256B swz
  __shared__ __align__(16) char BhB[16384], BlB[16384];  // 128 cols x 128B swz
  const int tid = threadIdx.x;
  const int w = tid >> 6, l = tid & 63;
  const long rowBase = (long)blockIdx.x * 32;
  const int rw = w & 1, ch2 = w >> 1;
  const int ar = rw * 16 + (l & 15);
  const int crow = rw * 16 + ((l >> 4) << 2);

  #pragma unroll
  for (int q = 0; q < 4; ++q) {
    int t = tid + 256 * q;                  // 0..1023
    int r = t >> 5, k4 = (t & 31) << 2;
    float4 v = *(const float4*)&xcat[(rowBase + r) * 128 + k4];
    ushort4 h4, l4;
    h4.x = f2bf(v.x); l4.x = f2bf(v.x - bf2f(h4.x));
    h4.y = f2bf(v.y); l4.y = f2bf(v.y - bf2f(h4.y));
    h4.z = f2bf(v.z); l4.z = f2bf(v.z - bf2f(h4.z));
    h4.w = f2bf(v.w); l4.w = f2bf(v.w - bf2f(h4.w));
    *(ushort4*)(AhB + swz256(r, k4 * 2)) = h4;
    *(ushort4*)(AlB + swz256(r, k4 * 2)) = l4;
  }
  __syncthreads();

  f32x4 acc[4];
  #pragma unroll
  for (int fc = 0; fc < 4; ++fc) acc[fc] = (f32x4){0.f, 0.f, 0.f, 0.f};
  for (int k0 = 0; k0 < 128; k0 += 64) {
    #pragma unroll
    for (int q = 0; q < 4; ++q) {
      int lin = tid + 256 * q;
      int n = lin >> 3, k8 = (lin & 7) << 3;
      *(uint4*)(BhB + swz128(n, k8 * 2)) = *(const uint4*)&Wph[n * 128 + k0 + k8];
      *(uint4*)(BlB + swz128(n, k8 * 2)) = *(const uint4*)&Wpl[n * 128 + k0 + k8];
    }
    __syncthreads();
    #pragma unroll
    for (int ks = 0; ks < 2; ++ks) {
      const int ko = ks * 32 + (l >> 4) * 8;
      short8 ah  = *(const short8*)(AhB + swz256(ar, (k0 + ko) * 2));
      short8 al8 = *(const short8*)(AlB + swz256(ar, (k0 + ko) * 2));
      #pragma unroll
      for (int fc = 0; fc < 4; ++fc) {
        const int c = ch2 * 64 + fc * 16 + (l & 15);
        short8 bh  = *(const short8*)(BhB + swz128(c, ko * 2));
        short8 bl8 = *(const short8*)(BlB + swz128(c, ko * 2));
        acc[fc] = __builtin_amdgcn_mfma_f32_16x16x32_bf16(al8, bh, acc[fc], 0, 0, 0);
        acc[fc] = __builtin_amdgcn_mfma_f32_16x16x32_bf16(ah, bl8, acc[fc], 0, 0, 0);
        acc[fc] = __builtin_amdgcn_mfma_f32_16x16x32_bf16(ah, bh, acc[fc], 0, 0, 0);
      }
    }
    __syncthreads();
  }

  // epilogue: write xp; overwrite A-tile with bf16-split xp
  #pragma unroll
  for (int fc = 0; fc < 4; ++fc) {
    int col = ch2 * 64 + fc * 16 + (l & 15);
    float bv = bp[col];
    #pragma unroll
    for (int i = 0; i < 4; ++i) {
      int lr = crow + i;
      float v = fmaxf(acc[fc][i] + bv, 0.f);
      xp[(rowBase + lr) * 128 + col] = v;
      ushort h = f2bf(v);
      *(ushort*)(AhB + swz256(lr, col * 2)) = h;
      *(ushort*)(AlB + swz256(lr, col * 2)) = f2bf(v - bf2f(h));
    }
  }

  // GEMM2: zb = xp @ be2
  #pragma unroll
  for (int fc = 0; fc < 4; ++fc) acc[fc] = (f32x4){0.f, 0.f, 0.f, 0.f};
  for (int k0 = 0; k0 < 128; k0 += 64) {
    __syncthreads();   // A writes visible (first iter) / prior B reads done
    #pragma unroll
    for (int q = 0; q < 4; ++q) {
      int lin = tid + 256 * q;
      int n = lin >> 3, k8 = (lin & 7) << 3;
      *(uint4*)(BhB + swz128(n, k8 * 2)) = *(const uint4*)&be2h[n * 128 + k0 + k8];
      *(uint4*)(BlB + swz128(n, k8 * 2)) = *(const uint4*)&be2l[n * 128 + k0 + k8];
    }
    __syncthreads();
    #pragma unroll
    for (int ks = 0; ks < 2; ++ks) {
      const int ko = ks * 32 + (l >> 4) * 8;
      short8 ah  = *(const short8*)(AhB + swz256(ar, (k0 + ko) * 2));
      short8 al8 = *(const short8*)(AlB + swz256(ar, (k0 + ko) * 2));
      #pragma unroll
      for (int fc = 0; fc < 4; ++fc) {
        const int c = ch2 * 64 + fc * 16 + (l & 15);
        short8 bh  = *(const short8*)(BhB + swz128(c, ko * 2));
        short8 bl8 = *(const short8*)(BlB + swz128(c, ko * 2));
        acc[fc] = __builtin_amdgcn_mfma_f32_16x16x32_bf16(al8, bh, acc[fc], 0, 0, 0);
        acc[fc] = __builtin_amdgcn_mfma_f32_16x16x32_bf16(ah, bl8, acc[fc], 0, 0, 0);
        acc[fc] = __builtin_amdgcn_mfma_f32_16x16x32_bf16(ah, bh, acc[fc], 0, 0, 0);
      }
    }
  }
  #pragma unroll
  for (int fc = 0; fc < 4; ++fc) {
    int col = ch2 * 64 + fc * 16 + (l & 15);
    #pragma unroll
    for (int i = 0; i < 4; ++i) {
      int lr = crow + i;
      zb[(rowBase + lr) * 128 + col] = acc[fc][i];
    }
  }
}

// ---------------------------------------------------------------------------
// cls v2: 32-row tiles, grid 64. o1 = relu(hg@Wcl1+b1); o2 = relu(o1@Wcl2+b2);
// out = o2@Wcl3 + bcl3 (per-wave partial over 64 cols, LDS merge).
// LDS ~57.6KB -> 2 blocks/CU.
// ---------------------------------------------------------------------------
__global__ __launch_bounds__(256, 2) void cls_kernel(
    const float* __restrict__ xnew,
    const ushort* __restrict__ W1h, const ushort* __restrict__ W1l,
    const float* __restrict__ b1,
    const ushort* __restrict__ W2h, const ushort* __restrict__ W2l,
    const float* __restrict__ b2,
    const float* __restrict__ Wcl3, const float* __restrict__ bcl3,
    float* __restrict__ out)
{
  __shared__ __align__(16) char O1h[8192], O1l[8192];    // o1 32 x 256B swz
  __shared__ __align__(16) char AhB[4096], AlB[4096];    // A chunk 32 x 128B swz
  __shared__ __align__(16) char BhB[16384], BlB[16384];  // B chunk 128 x 128B swz
  __shared__ float redP[64];                              // [32 rows][2]
  const int tid = threadIdx.x;
  const int w = tid >> 6, l = tid & 63;
  const long rowBase = (long)blockIdx.x * 32;
  const int rw = w & 1, ch2 = w >> 1;
  const int ar = rw * 16 + (l & 15);
  const int crow = rw * 16 + ((l >> 4) << 2);
  if (tid < 64) redP[tid] = 0.f;

  // phase 1: o1 = relu(hg @ Wcl1 + b1), K=256 (hg = [xnew | xnew+B2*128])
  f32x4 acc[4];
  #pragma unroll
  for (int fc = 0; fc < 4; ++fc) acc[fc] = (f32x4){0.f, 0.f, 0.f, 0.f};
  for (int k0 = 0; k0 < 256; k0 += 64) {
    const float* Ab = (k0 < 128) ? xnew : (xnew + (long)B2 * 128);
    const int kc = k0 & 127;
    #pragma unroll
    for (int q = 0; q < 2; ++q) {
      int lin = tid + 256 * q;                // 0..511
      int r = lin >> 4, k4 = (lin & 15) << 2;
      float4 v = *(const float4*)&Ab[(rowBase + r) * 128 + kc + k4];
      ushort4 h4, l4;
      h4.x = f2bf(v.x); l4.x = f2bf(v.x - bf2f(h4.x));
      h4.y = f2bf(v.y); l4.y = f2bf(v.y - bf2f(h4.y));
      h4.z = f2bf(v.z); l4.z = f2bf(v.z - bf2f(h4.z));
      h4.w = f2bf(v.w); l4.w = f2bf(v.w - bf2f(h4.w));
      *(ushort4*)(AhB + swz128(r, k4 * 2)) = h4;
      *(ushort4*)(AlB + swz128(r, k4 * 2)) = l4;
    }
    #pragma unroll
    for (int q = 0; q < 4; ++q) {
      int lin = tid + 256 * q;
      int n = lin >> 3, k8 = (lin & 7) << 3;
      *(uint4*)(BhB + swz128(n, k8 * 2)) = *(const uint4*)&W1h[(long)n * 256 + k0 + k8];
      *(uint4*)(BlB + swz128(n, k8 * 2)) = *(const uint4*)&W1l[(long)n * 256 + k0 + k8];
    }
    __syncthreads();
    #pragma unroll
    for (int ks = 0; ks < 2; ++ks) {
      const int ko = ks * 32 + (l >> 4) * 8;
      short8 ah  = *(const short8*)(AhB + swz128(ar, ko * 2));
      short8 al8 = *(const short8*)(AlB + swz128(ar, ko * 2));
      #pragma unroll
      for (int fc = 0; fc < 4; ++fc) {
        const int c = ch2 * 64 + fc * 16 + (l & 15);
        short8 bh  = *(const short8*)(BhB + swz128(c, ko * 2));
        short8 bl8 = *(const short8*)(BlB + swz128(c, ko * 2));
        acc[fc] = __builtin_amdgcn_mfma_f32_16x16x32_bf16(al8, bh, acc[fc], 0, 0, 0);
        acc[fc] = __builtin_amdgcn_mfma_f32_16x16x32_bf16(ah, bl8, acc[fc], 0, 0, 0);
        acc[fc] = __builtin_amdgcn_mfma_f32_16x16x32_bf16(ah, bh, acc[fc], 0, 0, 0);
      }
    }
    __syncthreads();
  }
  // o1 -> LDS bf16-split
  #pragma unroll
  for (int fc = 0; fc < 4; ++fc) {
    int col = ch2 * 64 + fc * 16 + (l & 15);
    float bv = b1[col];
    #pragma unroll
    for (int i = 0; i < 4; ++i) {
      int lr = crow + i;
      float v = fmaxf(acc[fc][i] + bv, 0.f);
      ushort h = f2bf(v);
      *(ushort*)(O1h + swz256(lr, col * 2)) = h;
      *(ushort*)(O1l + swz256(lr, col * 2)) = f2bf(v - bf2f(h));
    }
  }

  // phase 2: o2 = relu(o1 @ Wcl2 + b2), K=128
  #pragma unroll
  for (int fc = 0; fc < 4; ++fc) acc[fc] = (f32x4){0.f, 0.f, 0.f, 0.f};
  for (int k0 = 0; k0 < 128; k0 += 64) {
    __syncthreads();   // O1 writes visible (first iter) / prior B reads done
    #pragma unroll
    for (int q = 0; q < 4; ++q) {
      int lin = tid + 256 * q;
      int n = lin >> 3, k8 = (lin & 7) << 3;
      *(uint4*)(BhB + swz128(n, k8 * 2)) = *(const uint4*)&W2h[n * 128 + k0 + k8];
      *(uint4*)(BlB + swz128(n, k8 * 2)) = *(const uint4*)&W2l[n * 128 + k0 + k8];
    }
    __syncthreads();
    #pragma unroll
    for (int ks = 0; ks < 2; ++ks) {
      const int ko = ks * 32 + (l >> 4) * 8;
      short8 ah  = *(const short8*)(O1h + swz256(ar, (k0 + ko) * 2));
      short8 al8 = *(const short8*)(O1l + swz256(ar, (k0 + ko) * 2));
      #pragma unroll
      for (int fc = 0; fc < 4; ++fc) {
        const int c = ch2 * 64 + fc * 16 + (l & 15);
        short8 bh  = *(const short8*)(BhB + swz128(c, ko * 2));
        short8 bl8 = *(const short8*)(BlB + swz128(c, ko * 2));
        acc[fc] = __builtin_amdgcn_mfma_f32_16x16x32_bf16(al8, bh, acc[fc], 0, 0, 0);
        acc[fc] = __builtin_amdgcn_mfma_f32_16x16x32_bf16(ah, bl8, acc[fc], 0, 0, 0);
        acc[fc] = __builtin_amdgcn_mfma_f32_16x16x32_bf16(ah, bh, acc[fc], 0, 0, 0);
      }
    }
  }

  // phase 3: out = o2 @ Wcl3 + bcl3 (N=2); per-wave 64-col partial, LDS merge
  float p0[4] = {0.f, 0.f, 0.f, 0.f}, p1[4] = {0.f, 0.f, 0.f, 0.f};
  #pragma unroll
  for (int fc = 0; fc < 4; ++fc) {
    int col = ch2 * 64 + fc * 16 + (l & 15);
    float bv = b2[col];
    float w0 = Wcl3[col * 2], w1 = Wcl3[col * 2 + 1];
    #pragma unroll
    for (int i = 0; i < 4; ++i) {
      float v = fmaxf(acc[fc][i] + bv, 0.f);
      p0[i] = fmaf(v, w0, p0[i]);
      p1[i] = fmaf(v, w1, p1[i]);
    }
  }
  __syncthreads();   // redP zeros visible; prior phases done
  #pragma unroll
  for (int i = 0; i < 4; ++i) {
    #pragma unroll
    for (int m = 1; m < 16; m <<= 1) {
      p0[i] += __shfl_xor(p0[i], m);
      p1[i] += __shfl_xor(p1[i], m);
    }
    if ((l & 15) == 0) {
      atomicAdd(&redP[(crow + i) * 2 + 0], p0[i]);
      atomicAdd(&redP[(crow + i) * 2 + 1], p1[i]);
    }
  }
  __syncthreads();
  if (tid < 64) {
    int row = tid >> 1, c = tid & 1;
    out[(rowBase + row) * 2 + c] = redP[row * 2 + c] + bcl3[c];
  }
}

// ---------------------------------------------------------------------------
// zfold via MFMA (validated round 8/18 version).
// ---------------------------------------------------------------------------
__global__ __launch_bounds__(256, 1) void zfold_mfma_kernel(
    const float* __restrict__ xp,
    const ushort* __restrict__ We2h, const ushort* __restrict__ We2l,
    const float* __restrict__ interhb, const float* __restrict__ ia1,
    const float* __restrict__ ia2, const float* __restrict__ We1,
    const float* __restrict__ be1,
    float* __restrict__ aggA, float* __restrict__ aggB)
{
  __shared__ __align__(16) ushort Ah[2][64 * 72], Al[2][64 * 72];
  __shared__ __align__(16) ushort Bh[128 * 72], Bl[128 * 72];
  __shared__ float accAs[32 * 128], accBs[32 * 128];
  __shared__ float ehs[3][32][8];
  const int tid = threadIdx.x;
  const int w = tid >> 6, l = tid & 63;
  const int rg = blockIdx.x >> 2, kq = blockIdx.x & 3;
  const int i0 = rg * 32;

  for (int t = tid; t < 2048; t += 256) {
    int r = t >> 5, k4 = (t & 31) << 2;
    int gr = (r < 32) ? (i0 + r) : (B2 + i0 + r - 32);
    float4 v = *(const float4*)&xp[(long)gr * 128 + k4];
    int ch = k4 >> 6, ko = k4 & 63;
    ushort4 h4, l4;
    h4.x = f2bf(v.x); l4.x = f2bf(v.x - bf2f(h4.x));
    h4.y = f2bf(v.y); l4.y = f2bf(v.y - bf2f(h4.y));
    h4.z = f2bf(v.z); l4.z = f2bf(v.z - bf2f(h4.z));
    h4.w = f2bf(v.w); l4.w = f2bf(v.w - bf2f(h4.w));
    *(ushort4*)&Ah[ch][r * 72 + ko] = h4;
    *(ushort4*)&Al[ch][r * 72 + ko] = l4;
  }
  for (int t = tid; t < 768; t += 256) {
    int grp = t >> 8, rem = t & 255;
    int mm = rem >> 3, kk = rem & 7;
    int k = kq * 8 + kk;
    float u = (grp == 0) ? interhb[i0 + mm] : (grp == 1) ? ia1[i0 + mm] : ia2[i0 + mm];
    ehs[grp][mm][kk] = fmaxf(fmaf(u, We1[k], be1[k]), 0.f);
  }
  for (int t = tid; t < 4096; t += 256) { accAs[t] = 0.f; accBs[t] = 0.f; }

  float foldA[8][4] = {{0.f}}, foldB[8][4] = {{0.f}};
  const int ar = w * 16 + (l & 15);

  for (int kk = 0; kk < 8; ++kk) {
    const int k = kq * 8 + kk;
    f32x4 acc[8];
    #pragma unroll
    for (int fc = 0; fc < 8; ++fc) acc[fc] = (f32x4){0.f, 0.f, 0.f, 0.f};
    for (int ch = 0; ch < 2; ++ch) {
      __syncthreads();
      #pragma unroll
      for (int q = 0; q < 4; ++q) {
        int lin = tid + 256 * q;
        int n = lin >> 3, k8 = (lin & 7) << 3;
        *(uint4*)&Bh[n * 72 + k8] = *(const uint4*)&We2h[k * 16384 + n * 128 + ch * 64 + k8];
        *(uint4*)&Bl[n * 72 + k8] = *(const uint4*)&We2l[k * 16384 + n * 128 + ch * 64 + k8];
      }
      __syncthreads();
      #pragma unroll
      for (int ks = 0; ks < 2; ++ks) {
        const int ko = ks * 32 + (l >> 4) * 8;
        short8 ah  = *(const short8*)&Ah[ch][ar * 72 + ko];
        short8 al8 = *(const short8*)&Al[ch][ar * 72 + ko];
        #pragma unroll
        for (int fc = 0; fc < 8; ++fc) {
          const int c = fc * 16 + (l & 15);
          short8 bh  = *(const short8*)&Bh[c * 72 + ko];
          short8 bl8 = *(const short8*)&Bl[c * 72 + ko];
          acc[fc] = __builtin_amdgcn_mfma_f32_16x16x32_bf16(al8, bh, acc[fc], 0, 0, 0);
          acc[fc] = __builtin_amdgcn_mfma_f32_16x16x32_bf16(ah, bl8, acc[fc], 0, 0, 0);
          acc[fc] = __builtin_amdgcn_mfma_f32_16x16x32_bf16(ah, bh, acc[fc], 0, 0, 0);
        }
      }
    }
    #pragma unroll
    for (int i = 0; i < 4; ++i) {
      int lr = w * 16 + ((l >> 4) << 2) + i;
      int m = lr & 31, up = lr >> 5;
      float eA = up ? ehs[0][m][kk] : ehs[1][m][kk];
      float eB = up ? ehs[2][m][kk] : ehs[0][m][kk];
      #pragma unroll
      for (int fc = 0; fc < 8; ++fc) {
        foldA[fc][i] = fmaf(eA, acc[fc][i], foldA[fc][i]);
        foldB[fc][i] = fmaf(eB, acc[fc][i], foldB[fc][i]);
      }
    }
  }
  #pragma unroll
  for (int i = 0; i < 4; ++i) {
    int lr = w * 16 + ((l >> 4) << 2) + i;
    int m = lr & 31;
    #pragma unroll
    for (int fc = 0; fc < 8; ++fc) {
      int c = fc * 16 + (l & 15);
      atomicAdd(&accAs[m * 128 + c], foldA[fc][i]);
      atomicAdd(&accBs[m * 128 + c], foldB[fc][i]);
    }
  }
  __syncthreads();
  for (int t = tid; t < 4096; t += 256) {
    int mm = t >> 7, c = t & 127;
    atomicAdd(&aggA[(long)(i0 + mm) * 128 + c], accAs[t]);
    atomicAdd(&aggB[(long)(i0 + mm) * 128 + c], accBs[t]);
  }
}

// ---------------------------------------------------------------------------
// FULLY-FUSED ALL-MFMA GraphConv + inline adjacency build (validated r18).
// ---------------------------------------------------------------------------
__global__ __launch_bounds__(512, 4) void gconv_kernel(
    const float* __restrict__ h1, const float* __restrict__ h2,
    const int* __restrict__ src1, const int* __restrict__ dst1,
    const int* __restrict__ src2, const int* __restrict__ dst2,
    const float* __restrict__ bg1,
    const ushort* __restrict__ W1h, const ushort* __restrict__ W1l,
    const ushort* __restrict__ W2h, const ushort* __restrict__ W2l,
    const float* __restrict__ bias2, const float* __restrict__ s1x,
    float* __restrict__ xcat)
{
  __shared__ __align__(16) char pool[66560];
  char* AhB = pool;
  char* AlB = pool + 16384;
  char* BhB = pool + 32768;
  char* BlB = pool + 49152;
  char* A2h = pool;
  char* A2l = pool + 8192;
  char* Byh = pool + 32768;
  char* Byl = pool + 49152;
  float* cs = (float*)(pool + 65536);
  float* cntS = (float*)(pool + 16384);
  float* rsIS = (float*)(pool + 24576);
  float* rsOS = (float*)(pool + 24832);

  const int tid = threadIdx.x;
  const int p = blockIdx.x;
  const int g = p >> 10;
  const int mloc = (p & 1023) * 2;
  const float* hsrc = g ? h2 : h1;
  if (tid < 256) cs[tid] = 0.f;

  const int w8 = tid >> 6, l = tid & 63;
  const int rw = w8 & 3;
  const int ch2 = w8 >> 2;
  const int ar = rw * 16 + (l & 15);
  const int crow = rw * 16 + ((l >> 4) << 2);

  #pragma unroll
  for (int q = 0; q < 4; ++q) {
    int lin = tid + 512 * q;
    int r = lin >> 5, k4 = (lin & 31) << 2;
    float4 v = make_float4(0.f, 0.f, 0.f, 0.f);
    if (r < 60) {
      const float* Ar = &hsrc[(long)(mloc * 30 + r) * 74];
      if (k4 + 4 <= 74) {
        float2 a = *(const float2*)&Ar[k4];
        float2 b = *(const float2*)&Ar[k4 + 2];
        v = make_float4(a.x, a.y, b.x, b.y);
      } else if (k4 + 2 <= 74) {
        float2 a = *(const float2*)&Ar[k4];
        v.x = a.x; v.y = a.y;
      }
    }
    ushort4 h4, l4;
    h4.x = f2bf(v.x); l4.x = f2bf(v.x - bf2f(h4.x));
    h4.y = f2bf(v.y); l4.y = f2bf(v.y - bf2f(h4.y));
    h4.z = f2bf(v.z); l4.z = f2bf(v.z - bf2f(h4.z));
    h4.w = f2bf(v.w); l4.w = f2bf(v.w - bf2f(h4.w));
    *(ushort4*)(AhB + swz256(r, k4 * 2)) = h4;
    *(ushort4*)(AlB + swz256(r, k4 * 2)) = l4;
  }
  __syncthreads();

  f32x4 acc[4];
  #pragma unroll
  for (int fc = 0; fc < 4; ++fc) acc[fc] = (f32x4){0.f, 0.f, 0.f, 0.f};
  for (int k0 = 0; k0 < 128; k0 += 64) {
    #pragma unroll
    for (int q = 0; q < 2; ++q) {
      int lin = tid + 512 * q;
      int n = lin >> 3, k8 = (lin & 7) << 3;
      *(uint4*)(BhB + swz128(n, k8 * 2)) = *(const uint4*)&W1h[n * 128 + k0 + k8];
      *(uint4*)(BlB + swz128(n, k8 * 2)) = *(const uint4*)&W1l[n * 128 + k0 + k8];
    }
    __syncthreads();
    #pragma unroll
    for (int ks = 0; ks < 2; ++ks) {
      const int ko = ks * 32 + (l >> 4) * 8;
      short8 ah  = *(const short8*)(AhB + swz256(ar, (k0 + ko) * 2));
      short8 al8 = *(const short8*)(AlB + swz256(ar, (k0 + ko) * 2));
      #pragma unroll
      for (int fc = 0; fc < 4; ++fc) {
        const int c = ch2 * 64 + fc * 16 + (l & 15);
        short8 bh  = *(const short8*)(BhB + swz128(c, ko * 2));
        short8 bl8 = *(const short8*)(BlB + swz128(c, ko * 2));
        acc[fc] = __builtin_amdgcn_mfma_f32_16x16x32_bf16(al8, bh, acc[fc], 0, 0, 0);
        acc[fc] = __builtin_amdgcn_mfma_f32_16x16x32_bf16(ah, bl8, acc[fc], 0, 0, 0);
        acc[fc] = __builtin_amdgcn_mfma_f32_16x16x32_bf16(ah, bh, acc[fc], 0, 0, 0);
      }
    }
    __syncthreads();
  }

  #pragma unroll
  for (int fc = 0; fc < 4; ++fc) {
    int n = ch2 * 64 + fc * 16 + (l & 15);
    ushort4 h4, l4;
    h4.x = f2bf(acc[fc][0]); l4.x = f2bf(acc[fc][0] - bf2f(h4.x));
    h4.y = f2bf(acc[fc][1]); l4.y = f2bf(acc[fc][1] - bf2f(h4.y));
    h4.z = f2bf(acc[fc][2]); l4.z = f2bf(acc[fc][2] - bf2f(h4.z));
    h4.w = f2bf(acc[fc][3]); l4.w = f2bf(acc[fc][3] - bf2f(h4.w));
    *(ushort4*)(Byh + swz128(n, crow * 2)) = h4;
    *(ushort4*)(Byl + swz128(n, crow * 2)) = l4;
  }
  for (int t = tid; t < 2176; t += 512) ((float*)(pool + 16384))[t] = 0.f;
  __syncthreads();

  if (tid < 2 * EPM) {
    int mol = tid / EPM, e = tid - mol * EPM;
    const int* srcp = g ? src2 : src1;
    const int* dstp = g ? dst2 : dst1;
    int m = mloc + mol;
    int s = srcp[m * EPM + e] - m * NPM;
    int d = dstp[m * EPM + e] - m * NPM;
    atomicAdd(&cntS[mol * 990 + d * 33 + s], 1.0f);
  }
  __syncthreads();

  if (tid < 60) {
    int mol = tid / 30, r = tid - mol * 30;
    float s = 0.f;
    for (int k = 0; k < 30; ++k) s += cntS[mol * 990 + r * 33 + k];
    rsIS[mol * 32 + r] = rsqrtf(fmaxf(s, 1.f));
  } else if (tid >= 64 && tid < 124) {
    int t2 = tid - 64;
    int mol = t2 / 30, sc = t2 - mol * 30;
    float s = 0.f;
    for (int d = 0; d < 30; ++d) s += cntS[mol * 990 + d * 33 + sc];
    rsOS[mol * 32 + sc] = rsqrtf(fmaxf(s, 1.f));
  }
  __syncthreads();

  for (int t = tid; t < 4096; t += 512) {
    int row = t >> 6, k = t & 63;
    float v = 0.f;
    if (row < 30) {
      if (k < 30) v = cntS[row * 33 + k] * rsIS[row] * rsOS[k];
    } else if (row < 60) {
      if (k >= 30 && k < 60)
        v = cntS[990 + (row - 30) * 33 + (k - 30)] * rsIS[32 + row - 30] * rsOS[32 + k - 30];
    }
    ushort h = f2bf(v);
    *(ushort*)(A2h + swz128(row, k * 2)) = h;
    *(ushort*)(A2l + swz128(row, k * 2)) = f2bf(v - bf2f(h));
  }
  __syncthreads();

  f32x4 acc2[4];
  #pragma unroll
  for (int fc = 0; fc < 4; ++fc) acc2[fc] = (f32x4){0.f, 0.f, 0.f, 0.f};
  #pragma unroll
  for (int ks = 0; ks < 2; ++ks) {
    const int ko = ks * 32 + (l >> 4) * 8;
    short8 ah  = *(const short8*)(A2h + swz128(ar, ko * 2));
    short8 al8 = *(const short8*)(A2l + swz128(ar, ko * 2));
    #pragma unroll
    for (int fc = 0; fc < 4; ++fc) {
      const int c = ch2 * 64 + fc * 16 + (l & 15);
      short8 bh  = *(const short8*)(Byh + swz128(c, ko * 2));
      short8 bl8 = *(const short8*)(Byl + swz128(c, ko * 2));
      acc2[fc] = __builtin_amdgcn_mfma_f32_16x16x32_bf16(al8, bh, acc2[fc], 0, 0, 0);
      acc2[fc] = __builtin_amdgcn_mfma_f32_16x16x32_bf16(ah, bl8, acc2[fc], 0, 0, 0);
      acc2[fc] = __builtin_amdgcn_mfma_f32_16x16x32_bf16(ah, bh, acc2[fc], 0, 0, 0);
    }
  }
  __syncthreads();

  #pragma unroll
  for (int fc = 0; fc < 4; ++fc) {
    int n = ch2 * 64 + fc * 16 + (l & 15);
    float bv = bg1[n];
    float t0 = fmaxf(acc2[fc][0] + bv, 0.f);
    float t1v = fmaxf(acc2[fc][1] + bv, 0.f);
    float t2v = fmaxf(acc2[fc][2] + bv, 0.f);
    float t3 = fmaxf(acc2[fc][3] + bv, 0.f);
    ushort4 h4, l4;
    h4.x = f2bf(t0); l4.x = f2bf(t0 - bf2f(h4.x));
    h4.y = f2bf(t1v); l4.y = f2bf(t1v - bf2f(h4.y));
    h4.z = f2bf(t2v); l4.z = f2bf(t2v - bf2f(h4.z));
    h4.w = f2bf(t3); l4.w = f2bf(t3 - bf2f(h4.w));
    *(ushort4*)(Byh + swz128(n, crow * 2)) = h4;
    *(ushort4*)(Byl + swz128(n, crow * 2)) = l4;
  }
  __syncthreads();

  #pragma unroll
  for (int fc = 0; fc < 4; ++fc) acc2[fc] = (f32x4){0.f, 0.f, 0.f, 0.f};
  #pragma unroll
  for (int ks = 0; ks < 2; ++ks) {
    const int ko = ks * 32 + (l >> 4) * 8;
    short8 ah  = *(const short8*)(A2h + swz128(ar, ko * 2));
    short8 al8 = *(const short8*)(A2l + swz128(ar, ko * 2));
    #pragma unroll
    for (int fc = 0; fc < 4; ++fc) {
      const int c = ch2 * 64 + fc * 16 + (l & 15);
      short8 bh  = *(const short8*)(Byh + swz128(c, ko * 2));
      short8 bl8 = *(const short8*)(Byl + swz128(c, ko * 2));
      acc2[fc] = __builtin_amdgcn_mfma_f32_16x16x32_bf16(al8, bh, acc2[fc], 0, 0, 0);
      acc2[fc] = __builtin_amdgcn_mfma_f32_16x16x32_bf16(ah, bl8, acc2[fc], 0, 0, 0);
      acc2[fc] = __builtin_amdgcn_mfma_f32_16x16x32_bf16(ah, bh, acc2[fc], 0, 0, 0);
    }
  }
  __syncthreads();

  #pragma unroll
  for (int fc = 0; fc < 4; ++fc) {
    int n = ch2 * 64 + fc * 16 + (l & 15);
    #pragma unroll
    for (int i = 0; i < 4; ++i) {
      int r = crow + i;
      ushort h = f2bf(acc2[fc][i]);
      *(ushort*)(AhB + swz256(r, n * 2)) = h;
      *(ushort*)(AlB + swz256(r, n * 2)) = f2bf(acc2[fc][i] - bf2f(h));
    }
  }

  #pragma unroll
  for (int fc = 0; fc < 4; ++fc) acc[fc] = (f32x4){0.f, 0.f, 0.f, 0.f};
  for (int k0 = 0; k0 < 128; k0 += 64) {
    __syncthreads();
    #pragma unroll
    for (int q = 0; q < 2; ++q) {
      int lin = tid + 512 * q;
      int n = lin >> 3, k8 = (lin & 7) << 3;
      *(uint4*)(BhB + swz128(n, k8 * 2)) = *(const uint4*)&W2h[n * 128 + k0 + k8];
      *(uint4*)(BlB + swz128(n, k8 * 2)) = *(const uint4*)&W2l[n * 128 + k0 + k8];
    }
    __syncthreads();
    #pragma unroll
    for (int ks = 0; ks < 2; ++ks) {
      const int ko = ks * 32 + (l >> 4) * 8;
      short8 ah  = *(const short8*)(AhB + swz256(ar, (k0 + ko) * 2));
      short8 al8 = *(const short8*)(AlB + swz256(ar, (k0 + ko) * 2));
      #pragma unroll
      for (int fc = 0; fc < 4; ++fc) {
        const int c = ch2 * 64 + fc * 16 + (l & 15);
        short8 bh  = *(const short8*)(BhB + swz128(c, ko * 2));
        short8 bl8 = *(const short8*)(BlB + swz128(c, ko * 2));
        acc[fc] = __builtin_amdgcn_mfma_f32_16x16x32_bf16(al8, bh, acc[fc], 0, 0, 0);
        acc[fc] = __builtin_amdgcn_mfma_f32_16x16x32_bf16(ah, bl8, acc[fc], 0, 0, 0);
        acc[fc] = __builtin_amdgcn_mfma_f32_16x16x32_bf16(ah, bh, acc[fc], 0, 0, 0);
      }
    }
  }
  __syncthreads();

  #pragma unroll
  for (int fc = 0; fc < 4; ++fc) {
    int col = ch2 * 64 + fc * 16 + (l & 15);
    float bv = bias2[col];
    float s0 = 0.f, s1 = 0.f;
    #pragma unroll
    for (int i = 0; i < 4; ++i) {
      int lr = crow + i;
      if (lr < 60) {
        float v = fmaxf(acc[fc][i] + bv, 0.f);
        if (lr < NPM) s0 += v; else s1 += v;
      }
    }
    s0 += __shfl_down(s0, 32); s0 += __shfl_down(s0, 16);
    s1 += __shfl_down(s1, 32); s1 += __shfl_down(s1, 16);
    if ((l >> 4) == 0) {
      atomicAdd(&cs[col], s0);
      atomicAdd(&cs[128 + col], s1);
    }
  }
  __syncthreads();
  if (tid < 256) {
    int moll = tid >> 7, c = tid & 127;
    int gm = p * 2 + moll;
    int gg = gm >> 11, mm = gm & 2047;
    float sf = gg ? (1.f - s1x[mm]) : s1x[mm];
    xcat[(long)gm * 128 + c] = cs[moll * 128 + c] * (1.f / 30.f) * sf;
  }
}

// ---------------------------------------------------------------------------
extern "C" void kernel_launch(void* const* d_in, const int* in_sizes, int n_in,
                              void* d_out, int out_size, void* d_ws, size_t ws_size,
                              hipStream_t stream)
{
  const float* h1   = (const float*)d_in[0];
  const float* h2   = (const float*)d_in[1];
  const float* s1x  = (const float*)d_in[2];
  const float* ihb  = (const float*)d_in[3];
  const float* ia1  = (const float*)d_in[4];
  const float* ia2  = (const float*)d_in[5];
  const float* Wg1  = (const float*)d_in[6];
  const float* bg1  = (const float*)d_in[7];
  const float* Wg2  = (const float*)d_in[8];
  const float* bg2  = (const float*)d_in[9];
  const float* Wp   = (const float*)d_in[10];
  const float* bp   = (const float*)d_in[11];
  const float* We1  = (const float*)d_in[12];
  const float* be1  = (const float*)d_in[13];
  const float* We2  = (const float*)d_in[14];
  const float* be2  = (const float*)d_in[15];
  const float* bnn  = (const float*)d_in[16];
  const float* Wih  = (const float*)d_in[17];
  const float* bih  = (const float*)d_in[18];
  const float* Whh  = (const float*)d_in[19];
  const float* bhh  = (const float*)d_in[20];
  const float* Wcl1 = (const float*)d_in[21];
  const float* bcl1 = (const float*)d_in[22];
  const float* Wcl2 = (const float*)d_in[23];
  const float* bcl2 = (const float*)d_in[24];
  const float* Wcl3 = (const float*)d_in[25];
  const float* bcl3 = (const float*)d_in[26];
  const int*   src1 = (const int*)d_in[27];
  const int*   dst1 = (const int*)d_in[28];
  const int*   src2 = (const int*)d_in[29];
  const int*   dst2 = (const int*)d_in[30];
  float* out = (float*)d_out;
  float* ws  = (float*)d_ws;

  float* dwn  = ws + 35389440;

  float* xcat = dwn;
  float* xp   = dwn + 524288;
  float* zb   = dwn + 1048576;
  float* aggA = dwn + 1572864;
  float* aggB = dwn + 1835008;
  float* xnew = dwn + 2097152;

  ushort* wt     = (ushort*)(dwn + 6815744);
  ushort* WpTh   = wt;               ushort* WpTl   = wt + 16384;
  ushort* be2Th  = wt + 32768;       ushort* be2Tl  = wt + 49152;
  ushort* WihTh  = wt + 65536;       ushort* WihTl  = wt + 114688;
  ushort* WhhTh  = wt + 163840;      ushort* WhhTl  = wt + 212992;
  ushort* Wcl1Th = wt + 262144;      ushort* Wcl1Tl = wt + 294912;
  ushort* Wcl2Th = wt + 327680;      ushort* Wcl2Tl = wt + 344064;
  ushort* Wg1Th  = wt + 360448;      ushort* Wg1Tl  = wt + 376832;
  ushort* Wg2Th  = wt + 393216;      ushort* Wg2Tl  = wt + 409600;
  ushort* We2h   = wt + 425984;      ushort* We2l   = wt + 950272;

  // ---- fused weight prep (8 weights in one launch) ----
  PrepDescs pd;
  const float* Ws_[8]  = {Wp, be2, Wih, Whh, Wcl1, Wcl2, Wg1, Wg2};
  ushort* his[8]       = {WpTh, be2Th, WihTh, WhhTh, Wcl1Th, Wcl2Th, Wg1Th, Wg2Th};
  ushort* los[8]       = {WpTl, be2Tl, WihTl, WhhTl, Wcl1Tl, Wcl2Tl, Wg1Tl, Wg2Tl};
  int kr[8]   = {128, 128, 128, 128, 256, 128, 74, 128};
  int kp[8]   = {128, 128, 128, 128, 256, 128, 128, 128};
  int nn[8]   = {128, 128, 384, 384, 128, 128, 128, 128};
  int acc_blk = 0;
  for (int i = 0; i < 8; ++i) {
    pd.W[i] = Ws_[i]; pd.hi[i] = his[i]; pd.lo[i] = los[i];
    pd.Kreal[i] = kr[i]; pd.Kpad[i] = kp[i]; pd.N[i] = nn[i];
    pd.blk0[i] = acc_blk;
    acc_blk += (nn[i] * (kp[i] >> 3) + 255) / 256;
  }
  pd.blk0[8] = acc_blk;
  prep_all_kernel<<<acc_blk, 256, 0, stream>>>(pd);
  prep_we2_kernel<<<256, 256, 0, stream>>>(We2, We2h, We2l);

  // ---- fully-fused GraphConv (adjacency built in-block) ----
  gconv_kernel<<<2048, 512, 0, stream>>>(h1, h2, src1, dst1, src2, dst2,
                                         bg1, Wg1Th, Wg1Tl, Wg2Th, Wg2Tl,
                                         bg2, s1x, xcat);

  // ---- solvent-system MPNN + fused GRU + classifier ----
  xpzb_kernel<<<128, 256, 0, stream>>>(xcat, WpTh, WpTl, bp, be2Th, be2Tl, xp, zb);
  hipMemsetAsync(aggA, 0, 2 * 262144 * sizeof(float), stream);
  zfold_mfma_kernel<<<256, 256, 0, stream>>>(xp, We2h, We2l, ihb, ia1, ia2,
                                             We1, be1, aggA, aggB);
  grufuse_kernel<<<512, 256, 0, stream>>>(aggA, aggB, zb, bnn, xp,
                                          WihTh, WihTl, bih, WhhTh, WhhTl, bhh,
                                          xnew);
  cls_kernel<<<64, 256, 0, stream>>>(xnew, Wcl1Th, Wcl1Tl, bcl1,
                                     Wcl2Th, Wcl2Tl, bcl2, Wcl3, bcl3, out);
}

// Round 21
// 166.013 us; speedup vs baseline: 1.0580x; 1.0206x over previous
//
#include <hip/hip_runtime.h>
#include <hip/hip_bf16.h>
#include <math.h>

#define B2    2048
#define NPM   30
#define EPM   120

typedef __attribute__((ext_vector_type(8))) short short8;
typedef __attribute__((ext_vector_type(4))) float f32x4;

__device__ __forceinline__ ushort f2bf(float x) {
  unsigned u = __float_as_uint(x);
  return (ushort)((u + 0x7FFFu + ((u >> 16) & 1u)) >> 16);
}
__device__ __forceinline__ float bf2f(ushort h) {
  return __uint_as_float(((unsigned)h) << 16);
}

// swizzled byte offsets: 128B rows (per-chunk tiles) and 256B rows (full-K A)
__device__ __forceinline__ int swz128(int r, int kb) { return r * 128 + (kb ^ ((r & 7) << 4)); }
__device__ __forceinline__ int swz256(int r, int kb) { return r * 256 + (kb ^ ((r & 15) << 4)); }

// ---------------------------------------------------------------------------
// prep_all: 9 weight preps in one launch. Entries 0-7: W[Kreal][N] -> bf16
// split [N][Kpad]. Entry 8: We2 [32][128][128] -> per-k transposed split.
// ---------------------------------------------------------------------------
struct PrepDescs {
  const float* W[9];
  ushort* hi[9];
  ushort* lo[9];
  int Kreal[9], Kpad[9], N[9];
  int blk0[10];
};

__global__ __launch_bounds__(256) void prep_all_kernel(PrepDescs d)
{
  int b = blockIdx.x;
  int di = 0;
  #pragma unroll
  for (int j = 1; j < 9; ++j) if (b >= d.blk0[j]) di = j;
  if (di == 8) {
    // We2 mode: [32][128][128] -> hi/lo[k][n][d]
    int idx = (b - d.blk0[8]) * 256 + threadIdx.x;   // 0..65535
    const float* We2 = d.W[8];
    ushort* hi = d.hi[8];
    ushort* lo = d.lo[8];
    int k = idx >> 11;
    int rem = idx & 2047;
    int n = rem >> 4;
    int d8 = (rem & 15) << 3;
    #pragma unroll
    for (int j = 0; j < 8; ++j) {
      int dd = d8 + j;
      float x = We2[k * 16384 + dd * 128 + n];
      ushort h = f2bf(x);
      hi[k * 16384 + n * 128 + dd] = h;
      lo[k * 16384 + n * 128 + dd] = f2bf(x - bf2f(h));
    }
    return;
  }
  int idx = (b - d.blk0[di]) * 256 + threadIdx.x;
  int Kp8 = d.Kpad[di] >> 3;
  int tot = d.N[di] * Kp8;
  if (idx >= tot) return;
  int n = idx / Kp8;
  int k8 = (idx - n * Kp8) << 3;
  const float* W = d.W[di];
  ushort* hi = d.hi[di];
  ushort* lo = d.lo[di];
  int Kreal = d.Kreal[di], Kpad = d.Kpad[di], N = d.N[di];
  #pragma unroll
  for (int j = 0; j < 8; ++j) {
    int k = k8 + j;
    float x = (k < Kreal) ? W[(long)k * N + n] : 0.f;
    ushort h = f2bf(x);
    hi[(long)n * Kpad + k] = h;
    lo[(long)n * Kpad + k] = f2bf(x - bf2f(h));
  }
}

// ---------------------------------------------------------------------------
// grufuse v2 (validated round 15): 32x32 tiles, 512 blocks.
// ---------------------------------------------------------------------------
__global__ __launch_bounds__(256, 4) void grufuse_kernel(
    const float* __restrict__ aggA, const float* __restrict__ aggB,
    const float* __restrict__ zb, const float* __restrict__ bnn,
    const float* __restrict__ xp,
    const ushort* __restrict__ Wihh, const ushort* __restrict__ Wihl,
    const float* __restrict__ bih,
    const ushort* __restrict__ Whhh, const ushort* __restrict__ Whhl,
    const float* __restrict__ bhh,
    float* __restrict__ xnew)
{
  __shared__ __align__(16) char A1h[8192], A1l[8192];
  __shared__ __align__(16) char A2h[8192], A2l[8192];
  __shared__ __align__(16) char Bh[4096], Bl[4096];
  const int tid = threadIdx.x;
  const int w = tid >> 6, l = tid & 63;
  const int rt = blockIdx.x >> 2;
  const int qt = blockIdx.x & 3;
  const long rowBase = (long)rt * 32;
  const int rw = w & 1;
  const int cs = w >> 1;
  const int ar = rw * 16 + (l & 15);
  const int crow = rw * 16 + ((l >> 4) << 2);

  #pragma unroll
  for (int q = 0; q < 4; ++q) {
    int t = tid + 256 * q;
    int r = t >> 5, k4 = (t & 31) << 2;
    long gr = rowBase + r;
    long i = (gr < B2) ? gr : (gr - B2);
    float4 za = *(const float4*)&zb[i * 128 + k4];
    float4 zc = *(const float4*)&zb[(i + B2) * 128 + k4];
    float4 bn = *(const float4*)&bnn[k4];
    const float* ap = (gr < B2) ? &aggA[i * 128 + k4] : &aggB[i * 128 + k4];
    float4 ag = *(const float4*)ap;
    float4 xv;
    xv.x = fmaxf(ag.x + za.x + zc.x + bn.x, 0.f);
    xv.y = fmaxf(ag.y + za.y + zc.y + bn.y, 0.f);
    xv.z = fmaxf(ag.z + za.z + zc.z + bn.z, 0.f);
    xv.w = fmaxf(ag.w + za.w + zc.w + bn.w, 0.f);
    ushort4 h4, l4;
    h4.x = f2bf(xv.x); l4.x = f2bf(xv.x - bf2f(h4.x));
    h4.y = f2bf(xv.y); l4.y = f2bf(xv.y - bf2f(h4.y));
    h4.z = f2bf(xv.z); l4.z = f2bf(xv.z - bf2f(h4.z));
    h4.w = f2bf(xv.w); l4.w = f2bf(xv.w - bf2f(h4.w));
    *(ushort4*)(A1h + swz256(r, k4 * 2)) = h4;
    *(ushort4*)(A1l + swz256(r, k4 * 2)) = l4;
    float4 pv = *(const float4*)&xp[gr * 128 + k4];
    h4.x = f2bf(pv.x); l4.x = f2bf(pv.x - bf2f(h4.x));
    h4.y = f2bf(pv.y); l4.y = f2bf(pv.y - bf2f(h4.y));
    h4.z = f2bf(pv.z); l4.z = f2bf(pv.z - bf2f(h4.z));
    h4.w = f2bf(pv.w); l4.w = f2bf(pv.w - bf2f(h4.w));
    *(ushort4*)(A2h + swz256(r, k4 * 2)) = h4;
    *(ushort4*)(A2l + swz256(r, k4 * 2)) = l4;
  }
  __syncthreads();

  f32x4 rg = (f32x4){0,0,0,0}, zg = (f32x4){0,0,0,0};

  for (int gate = 0; gate < 3; ++gate) {
    f32x4 gi = (f32x4){0,0,0,0}, gh = (f32x4){0,0,0,0};
    for (int src = 0; src < 2; ++src) {
      const ushort* Wh = src ? Whhh : Wihh;
      const ushort* Wl = src ? Whhl : Wihl;
      const char* Ah = src ? A2h : A1h;
      const char* Al = src ? A2l : A1l;
      for (int k0 = 0; k0 < 128; k0 += 64) {
        __syncthreads();
        {
          int n = tid >> 3, k8 = (tid & 7) << 3;
          long wrow = (long)(gate * 128 + qt * 32 + n);
          *(uint4*)(Bh + swz128(n, k8 * 2)) = *(const uint4*)&Wh[wrow * 128 + k0 + k8];
          *(uint4*)(Bl + swz128(n, k8 * 2)) = *(const uint4*)&Wl[wrow * 128 + k0 + k8];
        }
        __syncthreads();
        f32x4 a = (src == 0) ? gi : gh;
        #pragma unroll
        for (int ks = 0; ks < 2; ++ks) {
          const int ko = ks * 32 + (l >> 4) * 8;
          short8 ah  = *(const short8*)(Ah + swz256(ar, (k0 + ko) * 2));
          short8 al8 = *(const short8*)(Al + swz256(ar, (k0 + ko) * 2));
          const int c = cs * 16 + (l & 15);
          short8 bh  = *(const short8*)(Bh + swz128(c, ko * 2));
          short8 bl8 = *(const short8*)(Bl + swz128(c, ko * 2));
          a = __builtin_amdgcn_mfma_f32_16x16x32_bf16(al8, bh, a, 0, 0, 0);
          a = __builtin_amdgcn_mfma_f32_16x16x32_bf16(ah, bl8, a, 0, 0, 0);
          a = __builtin_amdgcn_mfma_f32_16x16x32_bf16(ah, bh, a, 0, 0, 0);
        }
        if (src == 0) gi = a; else gh = a;
      }
    }
    int cg = qt * 32 + cs * 16 + (l & 15);
    float bi = bih[gate * 128 + cg], bh2 = bhh[gate * 128 + cg];
    #pragma unroll
    for (int i = 0; i < 4; ++i) {
      float a = gi[i] + bi;
      float b = gh[i] + bh2;
      if (gate == 0) {
        rg[i] = 1.f / (1.f + expf(-(a + b)));
      } else if (gate == 1) {
        zg[i] = 1.f / (1.f + expf(-(a + b)));
      } else {
        float ng = tanhf(a + rg[i] * b);
        long row = rowBase + crow + i;
        float h = xp[row * 128 + cg];
        xnew[row * 128 + cg] = (1.f - zg[i]) * ng + zg[i] * h;
      }
    }
  }
}

// ---------------------------------------------------------------------------
// xpzb v2: 32-row tiles, grid 128. Also zeroes aggA/aggB (fused memset).
// xp = relu(xcat@Wp+bp); zb = xp@be2 (xp kept in LDS).
// ---------------------------------------------------------------------------
__global__ __launch_bounds__(256, 3) void xpzb_kernel(
    const float* __restrict__ xcat,
    const ushort* __restrict__ Wph, const ushort* __restrict__ Wpl,
    const float* __restrict__ bp,
    const ushort* __restrict__ be2h, const ushort* __restrict__ be2l,
    float* __restrict__ xp, float* __restrict__ zb,
    float* __restrict__ aggZero)          // 524288 floats to zero
{
  __shared__ __align__(16) char AhB[8192], AlB[8192];
  __shared__ __align__(16) char BhB[16384], BlB[16384];
  const int tid = threadIdx.x;
  const int w = tid >> 6, l = tid & 63;
  const long rowBase = (long)blockIdx.x * 32;
  const int rw = w & 1, ch2 = w >> 1;
  const int ar = rw * 16 + (l & 15);
  const int crow = rw * 16 + ((l >> 4) << 2);

  // fused memset: zero aggA/aggB (consumed by zfold next)
  {
    const float4 z4 = make_float4(0.f, 0.f, 0.f, 0.f);
    long base = (long)(blockIdx.x * 256 + tid) * 4;
    long stride = (long)gridDim.x * 256 * 4;
    for (long t = base; t < 524288; t += stride)
      *(float4*)&aggZero[t] = z4;
  }

  #pragma unroll
  for (int q = 0; q < 4; ++q) {
    int t = tid + 256 * q;
    int r = t >> 5, k4 = (t & 31) << 2;
    float4 v = *(const float4*)&xcat[(rowBase + r) * 128 + k4];
    ushort4 h4, l4;
    h4.x = f2bf(v.x); l4.x = f2bf(v.x - bf2f(h4.x));
    h4.y = f2bf(v.y); l4.y = f2bf(v.y - bf2f(h4.y));
    h4.z = f2bf(v.z); l4.z = f2bf(v.z - bf2f(h4.z));
    h4.w = f2bf(v.w); l4.w = f2bf(v.w - bf2f(h4.w));
    *(ushort4*)(AhB + swz256(r, k4 * 2)) = h4;
    *(ushort4*)(AlB + swz256(r, k4 * 2)) = l4;
  }
  __syncthreads();

  f32x4 acc[4];
  #pragma unroll
  for (int fc = 0; fc < 4; ++fc) acc[fc] = (f32x4){0.f, 0.f, 0.f, 0.f};
  for (int k0 = 0; k0 < 128; k0 += 64) {
    #pragma unroll
    for (int q = 0; q < 4; ++q) {
      int lin = tid + 256 * q;
      int n = lin >> 3, k8 = (lin & 7) << 3;
      *(uint4*)(BhB + swz128(n, k8 * 2)) = *(const uint4*)&Wph[n * 128 + k0 + k8];
      *(uint4*)(BlB + swz128(n, k8 * 2)) = *(const uint4*)&Wpl[n * 128 + k0 + k8];
    }
    __syncthreads();
    #pragma unroll
    for (int ks = 0; ks < 2; ++ks) {
      const int ko = ks * 32 + (l >> 4) * 8;
      short8 ah  = *(const short8*)(AhB + swz256(ar, (k0 + ko) * 2));
      short8 al8 = *(const short8*)(AlB + swz256(ar, (k0 + ko) * 2));
      #pragma unroll
      for (int fc = 0; fc < 4; ++fc) {
        const int c = ch2 * 64 + fc * 16 + (l & 15);
        short8 bh  = *(const short8*)(BhB + swz128(c, ko * 2));
        short8 bl8 = *(const short8*)(BlB + swz128(c, ko * 2));
        acc[fc] = __builtin_amdgcn_mfma_f32_16x16x32_bf16(al8, bh, acc[fc], 0, 0, 0);
        acc[fc] = __builtin_amdgcn_mfma_f32_16x16x32_bf16(ah, bl8, acc[fc], 0, 0, 0);
        acc[fc] = __builtin_amdgcn_mfma_f32_16x16x32_bf16(ah, bh, acc[fc], 0, 0, 0);
      }
    }
    __syncthreads();
  }

  #pragma unroll
  for (int fc = 0; fc < 4; ++fc) {
    int col = ch2 * 64 + fc * 16 + (l & 15);
    float bv = bp[col];
    #pragma unroll
    for (int i = 0; i < 4; ++i) {
      int lr = crow + i;
      float v = fmaxf(acc[fc][i] + bv, 0.f);
      xp[(rowBase + lr) * 128 + col] = v;
      ushort h = f2bf(v);
      *(ushort*)(AhB + swz256(lr, col * 2)) = h;
      *(ushort*)(AlB + swz256(lr, col * 2)) = f2bf(v - bf2f(h));
    }
  }

  #pragma unroll
  for (int fc = 0; fc < 4; ++fc) acc[fc] = (f32x4){0.f, 0.f, 0.f, 0.f};
  for (int k0 = 0; k0 < 128; k0 += 64) {
    __syncthreads();
    #pragma unroll
    for (int q = 0; q < 4; ++q) {
      int lin = tid + 256 * q;
      int n = lin >> 3, k8 = (lin & 7) << 3;
      *(uint4*)(BhB + swz128(n, k8 * 2)) = *(const uint4*)&be2h[n * 128 + k0 + k8];
      *(uint4*)(BlB + swz128(n, k8 * 2)) = *(const uint4*)&be2l[n * 128 + k0 + k8];
    }
    __syncthreads();
    #pragma unroll
    for (int ks = 0; ks < 2; ++ks) {
      const int ko = ks * 32 + (l >> 4) * 8;
      short8 ah  = *(const short8*)(AhB + swz256(ar, (k0 + ko) * 2));
      short8 al8 = *(const short8*)(AlB + swz256(ar, (k0 + ko) * 2));
      #pragma unroll
      for (int fc = 0; fc < 4; ++fc) {
        const int c = ch2 * 64 + fc * 16 + (l & 15);
        short8 bh  = *(const short8*)(BhB + swz128(c, ko * 2));
        short8 bl8 = *(const short8*)(BlB + swz128(c, ko * 2));
        acc[fc] = __builtin_amdgcn_mfma_f32_16x16x32_bf16(al8, bh, acc[fc], 0, 0, 0);
        acc[fc] = __builtin_amdgcn_mfma_f32_16x16x32_bf16(ah, bl8, acc[fc], 0, 0, 0);
        acc[fc] = __builtin_amdgcn_mfma_f32_16x16x32_bf16(ah, bh, acc[fc], 0, 0, 0);
      }
    }
  }
  #pragma unroll
  for (int fc = 0; fc < 4; ++fc) {
    int col = ch2 * 64 + fc * 16 + (l & 15);
    #pragma unroll
    for (int i = 0; i < 4; ++i) {
      int lr = crow + i;
      zb[(rowBase + lr) * 128 + col] = acc[fc][i];
    }
  }
}

// ---------------------------------------------------------------------------
// cls v2 (validated round 20): 32-row tiles, grid 64.
// ---------------------------------------------------------------------------
__global__ __launch_bounds__(256, 2) void cls_kernel(
    const float* __restrict__ xnew,
    const ushort* __restrict__ W1h, const ushort* __restrict__ W1l,
    const float* __restrict__ b1,
    const ushort* __restrict__ W2h, const ushort* __restrict__ W2l,
    const float* __restrict__ b2,
    const float* __restrict__ Wcl3, const float* __restrict__ bcl3,
    float* __restrict__ out)
{
  __shared__ __align__(16) char O1h[8192], O1l[8192];
  __shared__ __align__(16) char AhB[4096], AlB[4096];
  __shared__ __align__(16) char BhB[16384], BlB[16384];
  __shared__ float redP[64];
  const int tid = threadIdx.x;
  const int w = tid >> 6, l = tid & 63;
  const long rowBase = (long)blockIdx.x * 32;
  const int rw = w & 1, ch2 = w >> 1;
  const int ar = rw * 16 + (l & 15);
  const int crow = rw * 16 + ((l >> 4) << 2);
  if (tid < 64) redP[tid] = 0.f;

  f32x4 acc[4];
  #pragma unroll
  for (int fc = 0; fc < 4; ++fc) acc[fc] = (f32x4){0.f, 0.f, 0.f, 0.f};
  for (int k0 = 0; k0 < 256; k0 += 64) {
    const float* Ab = (k0 < 128) ? xnew : (xnew + (long)B2 * 128);
    const int kc = k0 & 127;
    #pragma unroll
    for (int q = 0; q < 2; ++q) {
      int lin = tid + 256 * q;
      int r = lin >> 4, k4 = (lin & 15) << 2;
      float4 v = *(const float4*)&Ab[(rowBase + r) * 128 + kc + k4];
      ushort4 h4, l4;
      h4.x = f2bf(v.x); l4.x = f2bf(v.x - bf2f(h4.x));
      h4.y = f2bf(v.y); l4.y = f2bf(v.y - bf2f(h4.y));
      h4.z = f2bf(v.z); l4.z = f2bf(v.z - bf2f(h4.z));
      h4.w = f2bf(v.w); l4.w = f2bf(v.w - bf2f(h4.w));
      *(ushort4*)(AhB + swz128(r, k4 * 2)) = h4;
      *(ushort4*)(AlB + swz128(r, k4 * 2)) = l4;
    }
    #pragma unroll
    for (int q = 0; q < 4; ++q) {
      int lin = tid + 256 * q;
      int n = lin >> 3, k8 = (lin & 7) << 3;
      *(uint4*)(BhB + swz128(n, k8 * 2)) = *(const uint4*)&W1h[(long)n * 256 + k0 + k8];
      *(uint4*)(BlB + swz128(n, k8 * 2)) = *(const uint4*)&W1l[(long)n * 256 + k0 + k8];
    }
    __syncthreads();
    #pragma unroll
    for (int ks = 0; ks < 2; ++ks) {
      const int ko = ks * 32 + (l >> 4) * 8;
      short8 ah  = *(const short8*)(AhB + swz128(ar, ko * 2));
      short8 al8 = *(const short8*)(AlB + swz128(ar, ko * 2));
      #pragma unroll
      for (int fc = 0; fc < 4; ++fc) {
        const int c = ch2 * 64 + fc * 16 + (l & 15);
        short8 bh  = *(const short8*)(BhB + swz128(c, ko * 2));
        short8 bl8 = *(const short8*)(BlB + swz128(c, ko * 2));
        acc[fc] = __builtin_amdgcn_mfma_f32_16x16x32_bf16(al8, bh, acc[fc], 0, 0, 0);
        acc[fc] = __builtin_amdgcn_mfma_f32_16x16x32_bf16(ah, bl8, acc[fc], 0, 0, 0);
        acc[fc] = __builtin_amdgcn_mfma_f32_16x16x32_bf16(ah, bh, acc[fc], 0, 0, 0);
      }
    }
    __syncthreads();
  }
  #pragma unroll
  for (int fc = 0; fc < 4; ++fc) {
    int col = ch2 * 64 + fc * 16 + (l & 15);
    float bv = b1[col];
    #pragma unroll
    for (int i = 0; i < 4; ++i) {
      int lr = crow + i;
      float v = fmaxf(acc[fc][i] + bv, 0.f);
      ushort h = f2bf(v);
      *(ushort*)(O1h + swz256(lr, col * 2)) = h;
      *(ushort*)(O1l + swz256(lr, col * 2)) = f2bf(v - bf2f(h));
    }
  }

  #pragma unroll
  for (int fc = 0; fc < 4; ++fc) acc[fc] = (f32x4){0.f, 0.f, 0.f, 0.f};
  for (int k0 = 0; k0 < 128; k0 += 64) {
    __syncthreads();
    #pragma unroll
    for (int q = 0; q < 4; ++q) {
      int lin = tid + 256 * q;
      int n = lin >> 3, k8 = (lin & 7) << 3;
      *(uint4*)(BhB + swz128(n, k8 * 2)) = *(const uint4*)&W2h[n * 128 + k0 + k8];
      *(uint4*)(BlB + swz128(n, k8 * 2)) = *(const uint4*)&W2l[n * 128 + k0 + k8];
    }
    __syncthreads();
    #pragma unroll
    for (int ks = 0; ks < 2; ++ks) {
      const int ko = ks * 32 + (l >> 4) * 8;
      short8 ah  = *(const short8*)(O1h + swz256(ar, (k0 + ko) * 2));
      short8 al8 = *(const short8*)(O1l + swz256(ar, (k0 + ko) * 2));
      #pragma unroll
      for (int fc = 0; fc < 4; ++fc) {
        const int c = ch2 * 64 + fc * 16 + (l & 15);
        short8 bh  = *(const short8*)(BhB + swz128(c, ko * 2));
        short8 bl8 = *(const short8*)(BlB + swz128(c, ko * 2));
        acc[fc] = __builtin_amdgcn_mfma_f32_16x16x32_bf16(al8, bh, acc[fc], 0, 0, 0);
        acc[fc] = __builtin_amdgcn_mfma_f32_16x16x32_bf16(ah, bl8, acc[fc], 0, 0, 0);
        acc[fc] = __builtin_amdgcn_mfma_f32_16x16x32_bf16(ah, bh, acc[fc], 0, 0, 0);
      }
    }
  }

  float p0[4] = {0.f, 0.f, 0.f, 0.f}, p1[4] = {0.f, 0.f, 0.f, 0.f};
  #pragma unroll
  for (int fc = 0; fc < 4; ++fc) {
    int col = ch2 * 64 + fc * 16 + (l & 15);
    float bv = b2[col];
    float w0 = Wcl3[col * 2], w1 = Wcl3[col * 2 + 1];
    #pragma unroll
    for (int i = 0; i < 4; ++i) {
      float v = fmaxf(acc[fc][i] + bv, 0.f);
      p0[i] = fmaf(v, w0, p0[i]);
      p1[i] = fmaf(v, w1, p1[i]);
    }
  }
  __syncthreads();
  #pragma unroll
  for (int i = 0; i < 4; ++i) {
    #pragma unroll
    for (int m = 1; m < 16; m <<= 1) {
      p0[i] += __shfl_xor(p0[i], m);
      p1[i] += __shfl_xor(p1[i], m);
    }
    if ((l & 15) == 0) {
      atomicAdd(&redP[(crow + i) * 2 + 0], p0[i]);
      atomicAdd(&redP[(crow + i) * 2 + 1], p1[i]);
    }
  }
  __syncthreads();
  if (tid < 64) {
    int row = tid >> 1, c = tid & 1;
    out[(rowBase + row) * 2 + c] = redP[row * 2 + c] + bcl3[c];
  }
}

// ---------------------------------------------------------------------------
// zfold via MFMA (validated round 8/18 version).
// ---------------------------------------------------------------------------
__global__ __launch_bounds__(256, 1) void zfold_mfma_kernel(
    const float* __restrict__ xp,
    const ushort* __restrict__ We2h, const ushort* __restrict__ We2l,
    const float* __restrict__ interhb, const float* __restrict__ ia1,
    const float* __restrict__ ia2, const float* __restrict__ We1,
    const float* __restrict__ be1,
    float* __restrict__ aggA, float* __restrict__ aggB)
{
  __shared__ __align__(16) ushort Ah[2][64 * 72], Al[2][64 * 72];
  __shared__ __align__(16) ushort Bh[128 * 72], Bl[128 * 72];
  __shared__ float accAs[32 * 128], accBs[32 * 128];
  __shared__ float ehs[3][32][8];
  const int tid = threadIdx.x;
  const int w = tid >> 6, l = tid & 63;
  const int rg = blockIdx.x >> 2, kq = blockIdx.x & 3;
  const int i0 = rg * 32;

  for (int t = tid; t < 2048; t += 256) {
    int r = t >> 5, k4 = (t & 31) << 2;
    int gr = (r < 32) ? (i0 + r) : (B2 + i0 + r - 32);
    float4 v = *(const float4*)&xp[(long)gr * 128 + k4];
    int ch = k4 >> 6, ko = k4 & 63;
    ushort4 h4, l4;
    h4.x = f2bf(v.x); l4.x = f2bf(v.x - bf2f(h4.x));
    h4.y = f2bf(v.y); l4.y = f2bf(v.y - bf2f(h4.y));
    h4.z = f2bf(v.z); l4.z = f2bf(v.z - bf2f(h4.z));
    h4.w = f2bf(v.w); l4.w = f2bf(v.w - bf2f(h4.w));
    *(ushort4*)&Ah[ch][r * 72 + ko] = h4;
    *(ushort4*)&Al[ch][r * 72 + ko] = l4;
  }
  for (int t = tid; t < 768; t += 256) {
    int grp = t >> 8, rem = t & 255;
    int mm = rem >> 3, kk = rem & 7;
    int k = kq * 8 + kk;
    float u = (grp == 0) ? interhb[i0 + mm] : (grp == 1) ? ia1[i0 + mm] : ia2[i0 + mm];
    ehs[grp][mm][kk] = fmaxf(fmaf(u, We1[k], be1[k]), 0.f);
  }
  for (int t = tid; t < 4096; t += 256) { accAs[t] = 0.f; accBs[t] = 0.f; }

  float foldA[8][4] = {{0.f}}, foldB[8][4] = {{0.f}};
  const int ar = w * 16 + (l & 15);

  for (int kk = 0; kk < 8; ++kk) {
    const int k = kq * 8 + kk;
    f32x4 acc[8];
    #pragma unroll
    for (int fc = 0; fc < 8; ++fc) acc[fc] = (f32x4){0.f, 0.f, 0.f, 0.f};
    for (int ch = 0; ch < 2; ++ch) {
      __syncthreads();
      #pragma unroll
      for (int q = 0; q < 4; ++q) {
        int lin = tid + 256 * q;
        int n = lin >> 3, k8 = (lin & 7) << 3;
        *(uint4*)&Bh[n * 72 + k8] = *(const uint4*)&We2h[k * 16384 + n * 128 + ch * 64 + k8];
        *(uint4*)&Bl[n * 72 + k8] = *(const uint4*)&We2l[k * 16384 + n * 128 + ch * 64 + k8];
      }
      __syncthreads();
      #pragma unroll
      for (int ks = 0; ks < 2; ++ks) {
        const int ko = ks * 32 + (l >> 4) * 8;
        short8 ah  = *(const short8*)&Ah[ch][ar * 72 + ko];
        short8 al8 = *(const short8*)&Al[ch][ar * 72 + ko];
        #pragma unroll
        for (int fc = 0; fc < 8; ++fc) {
          const int c = fc * 16 + (l & 15);
          short8 bh  = *(const short8*)&Bh[c * 72 + ko];
          short8 bl8 = *(const short8*)&Bl[c * 72 + ko];
          acc[fc] = __builtin_amdgcn_mfma_f32_16x16x32_bf16(al8, bh, acc[fc], 0, 0, 0);
          acc[fc] = __builtin_amdgcn_mfma_f32_16x16x32_bf16(ah, bl8, acc[fc], 0, 0, 0);
          acc[fc] = __builtin_amdgcn_mfma_f32_16x16x32_bf16(ah, bh, acc[fc], 0, 0, 0);
        }
      }
    }
    #pragma unroll
    for (int i = 0; i < 4; ++i) {
      int lr = w * 16 + ((l >> 4) << 2) + i;
      int m = lr & 31, up = lr >> 5;
      float eA = up ? ehs[0][m][kk] : ehs[1][m][kk];
      float eB = up ? ehs[2][m][kk] : ehs[0][m][kk];
      #pragma unroll
      for (int fc = 0; fc < 8; ++fc) {
        foldA[fc][i] = fmaf(eA, acc[fc][i], foldA[fc][i]);
        foldB[fc][i] = fmaf(eB, acc[fc][i], foldB[fc][i]);
      }
    }
  }
  #pragma unroll
  for (int i = 0; i < 4; ++i) {
    int lr = w * 16 + ((l >> 4) << 2) + i;
    int m = lr & 31;
    #pragma unroll
    for (int fc = 0; fc < 8; ++fc) {
      int c = fc * 16 + (l & 15);
      atomicAdd(&accAs[m * 128 + c], foldA[fc][i]);
      atomicAdd(&accBs[m * 128 + c], foldB[fc][i]);
    }
  }
  __syncthreads();
  for (int t = tid; t < 4096; t += 256) {
    int mm = t >> 7, c = t & 127;
    atomicAdd(&aggA[(long)(i0 + mm) * 128 + c], accAs[t]);
    atomicAdd(&aggB[(long)(i0 + mm) * 128 + c], accBs[t]);
  }
}

// ---------------------------------------------------------------------------
// FULLY-FUSED ALL-MFMA GraphConv + inline adjacency build (validated r18).
// ---------------------------------------------------------------------------
__global__ __launch_bounds__(512, 4) void gconv_kernel(
    const float* __restrict__ h1, const float* __restrict__ h2,
    const int* __restrict__ src1, const int* __restrict__ dst1,
    const int* __restrict__ src2, const int* __restrict__ dst2,
    const float* __restrict__ bg1,
    const ushort* __restrict__ W1h, const ushort* __restrict__ W1l,
    const ushort* __restrict__ W2h, const ushort* __restrict__ W2l,
    const float* __restrict__ bias2, const float* __restrict__ s1x,
    float* __restrict__ xcat)
{
  __shared__ __align__(16) char pool[66560];
  char* AhB = pool;
  char* AlB = pool + 16384;
  char* BhB = pool + 32768;
  char* BlB = pool + 49152;
  char* A2h = pool;
  char* A2l = pool + 8192;
  char* Byh = pool + 32768;
  char* Byl = pool + 49152;
  float* cs = (float*)(pool + 65536);
  float* cntS = (float*)(pool + 16384);
  float* rsIS = (float*)(pool + 24576);
  float* rsOS = (float*)(pool + 24832);

  const int tid = threadIdx.x;
  const int p = blockIdx.x;
  const int g = p >> 10;
  const int mloc = (p & 1023) * 2;
  const float* hsrc = g ? h2 : h1;
  if (tid < 256) cs[tid] = 0.f;

  const int w8 = tid >> 6, l = tid & 63;
  const int rw = w8 & 3;
  const int ch2 = w8 >> 2;
  const int ar = rw * 16 + (l & 15);
  const int crow = rw * 16 + ((l >> 4) << 2);

  #pragma unroll
  for (int q = 0; q < 4; ++q) {
    int lin = tid + 512 * q;
    int r = lin >> 5, k4 = (lin & 31) << 2;
    float4 v = make_float4(0.f, 0.f, 0.f, 0.f);
    if (r < 60) {
      const float* Ar = &hsrc[(long)(mloc * 30 + r) * 74];
      if (k4 + 4 <= 74) {
        float2 a = *(const float2*)&Ar[k4];
        float2 b = *(const float2*)&Ar[k4 + 2];
        v = make_float4(a.x, a.y, b.x, b.y);
      } else if (k4 + 2 <= 74) {
        float2 a = *(const float2*)&Ar[k4];
        v.x = a.x; v.y = a.y;
      }
    }
    ushort4 h4, l4;
    h4.x = f2bf(v.x); l4.x = f2bf(v.x - bf2f(h4.x));
    h4.y = f2bf(v.y); l4.y = f2bf(v.y - bf2f(h4.y));
    h4.z = f2bf(v.z); l4.z = f2bf(v.z - bf2f(h4.z));
    h4.w = f2bf(v.w); l4.w = f2bf(v.w - bf2f(h4.w));
    *(ushort4*)(AhB + swz256(r, k4 * 2)) = h4;
    *(ushort4*)(AlB + swz256(r, k4 * 2)) = l4;
  }
  __syncthreads();

  f32x4 acc[4];
  #pragma unroll
  for (int fc = 0; fc < 4; ++fc) acc[fc] = (f32x4){0.f, 0.f, 0.f, 0.f};
  for (int k0 = 0; k0 < 128; k0 += 64) {
    #pragma unroll
    for (int q = 0; q < 2; ++q) {
      int lin = tid + 512 * q;
      int n = lin >> 3, k8 = (lin & 7) << 3;
      *(uint4*)(BhB + swz128(n, k8 * 2)) = *(const uint4*)&W1h[n * 128 + k0 + k8];
      *(uint4*)(BlB + swz128(n, k8 * 2)) = *(const uint4*)&W1l[n * 128 + k0 + k8];
    }
    __syncthreads();
    #pragma unroll
    for (int ks = 0; ks < 2; ++ks) {
      const int ko = ks * 32 + (l >> 4) * 8;
      short8 ah  = *(const short8*)(AhB + swz256(ar, (k0 + ko) * 2));
      short8 al8 = *(const short8*)(AlB + swz256(ar, (k0 + ko) * 2));
      #pragma unroll
      for (int fc = 0; fc < 4; ++fc) {
        const int c = ch2 * 64 + fc * 16 + (l & 15);
        short8 bh  = *(const short8*)(BhB + swz128(c, ko * 2));
        short8 bl8 = *(const short8*)(BlB + swz128(c, ko * 2));
        acc[fc] = __builtin_amdgcn_mfma_f32_16x16x32_bf16(al8, bh, acc[fc], 0, 0, 0);
        acc[fc] = __builtin_amdgcn_mfma_f32_16x16x32_bf16(ah, bl8, acc[fc], 0, 0, 0);
        acc[fc] = __builtin_amdgcn_mfma_f32_16x16x32_bf16(ah, bh, acc[fc], 0, 0, 0);
      }
    }
    __syncthreads();
  }

  #pragma unroll
  for (int fc = 0; fc < 4; ++fc) {
    int n = ch2 * 64 + fc * 16 + (l & 15);
    ushort4 h4, l4;
    h4.x = f2bf(acc[fc][0]); l4.x = f2bf(acc[fc][0] - bf2f(h4.x));
    h4.y = f2bf(acc[fc][1]); l4.y = f2bf(acc[fc][1] - bf2f(h4.y));
    h4.z = f2bf(acc[fc][2]); l4.z = f2bf(acc[fc][2] - bf2f(h4.z));
    h4.w = f2bf(acc[fc][3]); l4.w = f2bf(acc[fc][3] - bf2f(h4.w));
    *(ushort4*)(Byh + swz128(n, crow * 2)) = h4;
    *(ushort4*)(Byl + swz128(n, crow * 2)) = l4;
  }
  for (int t = tid; t < 2176; t += 512) ((float*)(pool + 16384))[t] = 0.f;
  __syncthreads();

  if (tid < 2 * EPM) {
    int mol = tid / EPM, e = tid - mol * EPM;
    const int* srcp = g ? src2 : src1;
    const int* dstp = g ? dst2 : dst1;
    int m = mloc + mol;
    int s = srcp[m * EPM + e] - m * NPM;
    int d = dstp[m * EPM + e] - m * NPM;
    atomicAdd(&cntS[mol * 990 + d * 33 + s], 1.0f);
  }
  __syncthreads();

  if (tid < 60) {
    int mol = tid / 30, r = tid - mol * 30;
    float s = 0.f;
    for (int k = 0; k < 30; ++k) s += cntS[mol * 990 + r * 33 + k];
    rsIS[mol * 32 + r] = rsqrtf(fmaxf(s, 1.f));
  } else if (tid >= 64 && tid < 124) {
    int t2 = tid - 64;
    int mol = t2 / 30, sc = t2 - mol * 30;
    float s = 0.f;
    for (int d = 0; d < 30; ++d) s += cntS[mol * 990 + d * 33 + sc];
    rsOS[mol * 32 + sc] = rsqrtf(fmaxf(s, 1.f));
  }
  __syncthreads();

  for (int t = tid; t < 4096; t += 512) {
    int row = t >> 6, k = t & 63;
    float v = 0.f;
    if (row < 30) {
      if (k < 30) v = cntS[row * 33 + k] * rsIS[row] * rsOS[k];
    } else if (row < 60) {
      if (k >= 30 && k < 60)
        v = cntS[990 + (row - 30) * 33 + (k - 30)] * rsIS[32 + row - 30] * rsOS[32 + k - 30];
    }
    ushort h = f2bf(v);
    *(ushort*)(A2h + swz128(row, k * 2)) = h;
    *(ushort*)(A2l + swz128(row, k * 2)) = f2bf(v - bf2f(h));
  }
  __syncthreads();

  f32x4 acc2[4];
  #pragma unroll
  for (int fc = 0; fc < 4; ++fc) acc2[fc] = (f32x4){0.f, 0.f, 0.f, 0.f};
  #pragma unroll
  for (int ks = 0; ks < 2; ++ks) {
    const int ko = ks * 32 + (l >> 4) * 8;
    short8 ah  = *(const short8*)(A2h + swz128(ar, ko * 2));
    short8 al8 = *(const short8*)(A2l + swz128(ar, ko * 2));
    #pragma unroll
    for (int fc = 0; fc < 4; ++fc) {
      const int c = ch2 * 64 + fc * 16 + (l & 15);
      short8 bh  = *(const short8*)(Byh + swz128(c, ko * 2));
      short8 bl8 = *(const short8*)(Byl + swz128(c, ko * 2));
      acc2[fc] = __builtin_amdgcn_mfma_f32_16x16x32_bf16(al8, bh, acc2[fc], 0, 0, 0);
      acc2[fc] = __builtin_amdgcn_mfma_f32_16x16x32_bf16(ah, bl8, acc2[fc], 0, 0, 0);
      acc2[fc] = __builtin_amdgcn_mfma_f32_16x16x32_bf16(ah, bh, acc2[fc], 0, 0, 0);
    }
  }
  __syncthreads();

  #pragma unroll
  for (int fc = 0; fc < 4; ++fc) {
    int n = ch2 * 64 + fc * 16 + (l & 15);
    float bv = bg1[n];
    float t0 = fmaxf(acc2[fc][0] + bv, 0.f);
    float t1v = fmaxf(acc2[fc][1] + bv, 0.f);
    float t2v = fmaxf(acc2[fc][2] + bv, 0.f);
    float t3 = fmaxf(acc2[fc][3] + bv, 0.f);
    ushort4 h4, l4;
    h4.x = f2bf(t0); l4.x = f2bf(t0 - bf2f(h4.x));
    h4.y = f2bf(t1v); l4.y = f2bf(t1v - bf2f(h4.y));
    h4.z = f2bf(t2v); l4.z = f2bf(t2v - bf2f(h4.z));
    h4.w = f2bf(t3); l4.w = f2bf(t3 - bf2f(h4.w));
    *(ushort4*)(Byh + swz128(n, crow * 2)) = h4;
    *(ushort4*)(Byl + swz128(n, crow * 2)) = l4;
  }
  __syncthreads();

  #pragma unroll
  for (int fc = 0; fc < 4; ++fc) acc2[fc] = (f32x4){0.f, 0.f, 0.f, 0.f};
  #pragma unroll
  for (int ks = 0; ks < 2; ++ks) {
    const int ko = ks * 32 + (l >> 4) * 8;
    short8 ah  = *(const short8*)(A2h + swz128(ar, ko * 2));
    short8 al8 = *(const short8*)(A2l + swz128(ar, ko * 2));
    #pragma unroll
    for (int fc = 0; fc < 4; ++fc) {
      const int c = ch2 * 64 + fc * 16 + (l & 15);
      short8 bh  = *(const short8*)(Byh + swz128(c, ko * 2));
      short8 bl8 = *(const short8*)(Byl + swz128(c, ko * 2));
      acc2[fc] = __builtin_amdgcn_mfma_f32_16x16x32_bf16(al8, bh, acc2[fc], 0, 0, 0);
      acc2[fc] = __builtin_amdgcn_mfma_f32_16x16x32_bf16(ah, bl8, acc2[fc], 0, 0, 0);
      acc2[fc] = __builtin_amdgcn_mfma_f32_16x16x32_bf16(ah, bh, acc2[fc], 0, 0, 0);
    }
  }
  __syncthreads();

  #pragma unroll
  for (int fc = 0; fc < 4; ++fc) {
    int n = ch2 * 64 + fc * 16 + (l & 15);
    #pragma unroll
    for (int i = 0; i < 4; ++i) {
      int r = crow + i;
      ushort h = f2bf(acc2[fc][i]);
      *(ushort*)(AhB + swz256(r, n * 2)) = h;
      *(ushort*)(AlB + swz256(r, n * 2)) = f2bf(acc2[fc][i] - bf2f(h));
    }
  }

  #pragma unroll
  for (int fc = 0; fc < 4; ++fc) acc[fc] = (f32x4){0.f, 0.f, 0.f, 0.f};
  for (int k0 = 0; k0 < 128; k0 += 64) {
    __syncthreads();
    #pragma unroll
    for (int q = 0; q < 2; ++q) {
      int lin = tid + 512 * q;
      int n = lin >> 3, k8 = (lin & 7) << 3;
      *(uint4*)(BhB + swz128(n, k8 * 2)) = *(const uint4*)&W2h[n * 128 + k0 + k8];
      *(uint4*)(BlB + swz128(n, k8 * 2)) = *(const uint4*)&W2l[n * 128 + k0 + k8];
    }
    __syncthreads();
    #pragma unroll
    for (int ks = 0; ks < 2; ++ks) {
      const int ko = ks * 32 + (l >> 4) * 8;
      short8 ah  = *(const short8*)(AhB + swz256(ar, (k0 + ko) * 2));
      short8 al8 = *(const short8*)(AlB + swz256(ar, (k0 + ko) * 2));
      #pragma unroll
      for (int fc = 0; fc < 4; ++fc) {
        const int c = ch2 * 64 + fc * 16 + (l & 15);
        short8 bh  = *(const short8*)(BhB + swz128(c, ko * 2));
        short8 bl8 = *(const short8*)(BlB + swz128(c, ko * 2));
        acc[fc] = __builtin_amdgcn_mfma_f32_16x16x32_bf16(al8, bh, acc[fc], 0, 0, 0);
        acc[fc] = __builtin_amdgcn_mfma_f32_16x16x32_bf16(ah, bl8, acc[fc], 0, 0, 0);
        acc[fc] = __builtin_amdgcn_mfma_f32_16x16x32_bf16(ah, bh, acc[fc], 0, 0, 0);
      }
    }
  }
  __syncthreads();

  #pragma unroll
  for (int fc = 0; fc < 4; ++fc) {
    int col = ch2 * 64 + fc * 16 + (l & 15);
    float bv = bias2[col];
    float s0 = 0.f, s1 = 0.f;
    #pragma unroll
    for (int i = 0; i < 4; ++i) {
      int lr = crow + i;
      if (lr < 60) {
        float v = fmaxf(acc[fc][i] + bv, 0.f);
        if (lr < NPM) s0 += v; else s1 += v;
      }
    }
    s0 += __shfl_down(s0, 32); s0 += __shfl_down(s0, 16);
    s1 += __shfl_down(s1, 32); s1 += __shfl_down(s1, 16);
    if ((l >> 4) == 0) {
      atomicAdd(&cs[col], s0);
      atomicAdd(&cs[128 + col], s1);
    }
  }
  __syncthreads();
  if (tid < 256) {
    int moll = tid >> 7, c = tid & 127;
    int gm = p * 2 + moll;
    int gg = gm >> 11, mm = gm & 2047;
    float sf = gg ? (1.f - s1x[mm]) : s1x[mm];
    xcat[(long)gm * 128 + c] = cs[moll * 128 + c] * (1.f / 30.f) * sf;
  }
}

// ---------------------------------------------------------------------------
extern "C" void kernel_launch(void* const* d_in, const int* in_sizes, int n_in,
                              void* d_out, int out_size, void* d_ws, size_t ws_size,
                              hipStream_t stream)
{
  const float* h1   = (const float*)d_in[0];
  const float* h2   = (const float*)d_in[1];
  const float* s1x  = (const float*)d_in[2];
  const float* ihb  = (const float*)d_in[3];
  const float* ia1  = (const float*)d_in[4];
  const float* ia2  = (const float*)d_in[5];
  const float* Wg1  = (const float*)d_in[6];
  const float* bg1  = (const float*)d_in[7];
  const float* Wg2  = (const float*)d_in[8];
  const float* bg2  = (const float*)d_in[9];
  const float* Wp   = (const float*)d_in[10];
  const float* bp   = (const float*)d_in[11];
  const float* We1  = (const float*)d_in[12];
  const float* be1  = (const float*)d_in[13];
  const float* We2  = (const float*)d_in[14];
  const float* be2  = (const float*)d_in[15];
  const float* bnn  = (const float*)d_in[16];
  const float* Wih  = (const float*)d_in[17];
  const float* bih  = (const float*)d_in[18];
  const float* Whh  = (const float*)d_in[19];
  const float* bhh  = (const float*)d_in[20];
  const float* Wcl1 = (const float*)d_in[21];
  const float* bcl1 = (const float*)d_in[22];
  const float* Wcl2 = (const float*)d_in[23];
  const float* bcl2 = (const float*)d_in[24];
  const float* Wcl3 = (const float*)d_in[25];
  const float* bcl3 = (const float*)d_in[26];
  const int*   src1 = (const int*)d_in[27];
  const int*   dst1 = (const int*)d_in[28];
  const int*   src2 = (const int*)d_in[29];
  const int*   dst2 = (const int*)d_in[30];
  float* out = (float*)d_out;
  float* ws  = (float*)d_ws;

  float* dwn  = ws + 35389440;

  float* xcat = dwn;
  float* xp   = dwn + 524288;
  float* zb   = dwn + 1048576;
  float* aggA = dwn + 1572864;
  float* aggB = dwn + 1835008;
  float* xnew = dwn + 2097152;

  ushort* wt     = (ushort*)(dwn + 6815744);
  ushort* WpTh   = wt;               ushort* WpTl   = wt + 16384;
  ushort* be2Th  = wt + 32768;       ushort* be2Tl  = wt + 49152;
  ushort* WihTh  = wt + 65536;       ushort* WihTl  = wt + 114688;
  ushort* WhhTh  = wt + 163840;      ushort* WhhTl  = wt + 212992;
  ushort* Wcl1Th = wt + 262144;      ushort* Wcl1Tl = wt + 294912;
  ushort* Wcl2Th = wt + 327680;      ushort* Wcl2Tl = wt + 344064;
  ushort* Wg1Th  = wt + 360448;      ushort* Wg1Tl  = wt + 376832;
  ushort* Wg2Th  = wt + 393216;      ushort* Wg2Tl  = wt + 409600;
  ushort* We2h   = wt + 425984;      ushort* We2l   = wt + 950272;

  // ---- fused weight prep (9 weights incl. We2, one launch) ----
  PrepDescs pd;
  const float* Ws_[9]  = {Wp, be2, Wih, Whh, Wcl1, Wcl2, Wg1, Wg2, We2};
  ushort* his[9]       = {WpTh, be2Th, WihTh, WhhTh, Wcl1Th, Wcl2Th, Wg1Th, Wg2Th, We2h};
  ushort* los[9]       = {WpTl, be2Tl, WihTl, WhhTl, Wcl1Tl, Wcl2Tl, Wg1Tl, Wg2Tl, We2l};
  int kr[9]   = {128, 128, 128, 128, 256, 128, 74, 128, 0};
  int kp[9]   = {128, 128, 128, 128, 256, 128, 128, 128, 0};
  int nn[9]   = {128, 128, 384, 384, 128, 128, 128, 128, 0};
  int acc_blk = 0;
  for (int i = 0; i < 8; ++i) {
    pd.W[i] = Ws_[i]; pd.hi[i] = his[i]; pd.lo[i] = los[i];
    pd.Kreal[i] = kr[i]; pd.Kpad[i] = kp[i]; pd.N[i] = nn[i];
    pd.blk0[i] = acc_blk;
    acc_blk += (nn[i] * (kp[i] >> 3) + 255) / 256;
  }
  pd.W[8] = Ws_[8]; pd.hi[8] = his[8]; pd.lo[8] = los[8];
  pd.Kreal[8] = 0; pd.Kpad[8] = 0; pd.N[8] = 0;
  pd.blk0[8] = acc_blk;
  acc_blk += 256;                      // We2: 65536 threads / 256
  pd.blk0[9] = acc_blk;
  prep_all_kernel<<<acc_blk, 256, 0, stream>>>(pd);

  // ---- fully-fused GraphConv (adjacency built in-block) ----
  gconv_kernel<<<2048, 512, 0, stream>>>(h1, h2, src1, dst1, src2, dst2,
                                         bg1, Wg1Th, Wg1Tl, Wg2Th, Wg2Tl,
                                         bg2, s1x, xcat);

  // ---- solvent-system MPNN + fused GRU + classifier ----
  xpzb_kernel<<<128, 256, 0, stream>>>(xcat, WpTh, WpTl, bp, be2Th, be2Tl,
                                       xp, zb, aggA);
  zfold_mfma_kernel<<<256, 256, 0, stream>>>(xp, We2h, We2l, ihb, ia1, ia2,
                                             We1, be1, aggA, aggB);
  grufuse_kernel<<<512, 256, 0, stream>>>(aggA, aggB, zb, bnn, xp,
                                          WihTh, WihTl, bih, WhhTh, WhhTl, bhh,
                                          xnew);
  cls_kernel<<<64, 256, 0, stream>>>(xnew, Wcl1Th, Wcl1Tl, bcl1,
                                     Wcl2Th, Wcl2Tl, bcl2, Wcl3, bcl3, out);
}

// Round 22
// 164.804 us; speedup vs baseline: 1.0658x; 1.0073x over previous
//
#include <hip/hip_runtime.h>
#include <hip/hip_bf16.h>
#include <math.h>

#define B2    2048
#define NPM   30
#define EPM   120

typedef __attribute__((ext_vector_type(8))) short short8;
typedef __attribute__((ext_vector_type(4))) float f32x4;

__device__ __forceinline__ ushort f2bf(float x) {
  unsigned u = __float_as_uint(x);
  return (ushort)((u + 0x7FFFu + ((u >> 16) & 1u)) >> 16);
}
__device__ __forceinline__ float bf2f(ushort h) {
  return __uint_as_float(((unsigned)h) << 16);
}

// swizzled byte offsets: 128B rows (per-chunk tiles) and 256B rows (full-K A)
__device__ __forceinline__ int swz128(int r, int kb) { return r * 128 + (kb ^ ((r & 7) << 4)); }
__device__ __forceinline__ int swz256(int r, int kb) { return r * 256 + (kb ^ ((r & 15) << 4)); }

// ---------------------------------------------------------------------------
// prep_all: 9 weight preps in one launch. Entries 0-7: W[Kreal][N] -> bf16
// split [N][Kpad]. Entry 8: We2 [32][128][128] -> per-k transposed split.
// ---------------------------------------------------------------------------
struct PrepDescs {
  const float* W[9];
  ushort* hi[9];
  ushort* lo[9];
  int Kreal[9], Kpad[9], N[9];
  int blk0[10];
};

__global__ __launch_bounds__(256) void prep_all_kernel(PrepDescs d)
{
  int b = blockIdx.x;
  int di = 0;
  #pragma unroll
  for (int j = 1; j < 9; ++j) if (b >= d.blk0[j]) di = j;
  if (di == 8) {
    // We2 mode: [32][128][128] -> hi/lo[k][n][d]
    int idx = (b - d.blk0[8]) * 256 + threadIdx.x;   // 0..65535
    const float* We2 = d.W[8];
    ushort* hi = d.hi[8];
    ushort* lo = d.lo[8];
    int k = idx >> 11;
    int rem = idx & 2047;
    int n = rem >> 4;
    int d8 = (rem & 15) << 3;
    #pragma unroll
    for (int j = 0; j < 8; ++j) {
      int dd = d8 + j;
      float x = We2[k * 16384 + dd * 128 + n];
      ushort h = f2bf(x);
      hi[k * 16384 + n * 128 + dd] = h;
      lo[k * 16384 + n * 128 + dd] = f2bf(x - bf2f(h));
    }
    return;
  }
  int idx = (b - d.blk0[di]) * 256 + threadIdx.x;
  int Kp8 = d.Kpad[di] >> 3;
  int tot = d.N[di] * Kp8;
  if (idx >= tot) return;
  int n = idx / Kp8;
  int k8 = (idx - n * Kp8) << 3;
  const float* W = d.W[di];
  ushort* hi = d.hi[di];
  ushort* lo = d.lo[di];
  int Kreal = d.Kreal[di], Kpad = d.Kpad[di], N = d.N[di];
  #pragma unroll
  for (int j = 0; j < 8; ++j) {
    int k = k8 + j;
    float x = (k < Kreal) ? W[(long)k * N + n] : 0.f;
    ushort h = f2bf(x);
    hi[(long)n * Kpad + k] = h;
    lo[(long)n * Kpad + k] = f2bf(x - bf2f(h));
  }
}

// ---------------------------------------------------------------------------
// grufuse v2 (validated round 15): 32x32 tiles, 512 blocks.
// ---------------------------------------------------------------------------
__global__ __launch_bounds__(256, 4) void grufuse_kernel(
    const float* __restrict__ aggA, const float* __restrict__ aggB,
    const float* __restrict__ zb, const float* __restrict__ bnn,
    const float* __restrict__ xp,
    const ushort* __restrict__ Wihh, const ushort* __restrict__ Wihl,
    const float* __restrict__ bih,
    const ushort* __restrict__ Whhh, const ushort* __restrict__ Whhl,
    const float* __restrict__ bhh,
    float* __restrict__ xnew)
{
  __shared__ __align__(16) char A1h[8192], A1l[8192];
  __shared__ __align__(16) char A2h[8192], A2l[8192];
  __shared__ __align__(16) char Bh[4096], Bl[4096];
  const int tid = threadIdx.x;
  const int w = tid >> 6, l = tid & 63;
  const int rt = blockIdx.x >> 2;
  const int qt = blockIdx.x & 3;
  const long rowBase = (long)rt * 32;
  const int rw = w & 1;
  const int cs = w >> 1;
  const int ar = rw * 16 + (l & 15);
  const int crow = rw * 16 + ((l >> 4) << 2);

  #pragma unroll
  for (int q = 0; q < 4; ++q) {
    int t = tid + 256 * q;
    int r = t >> 5, k4 = (t & 31) << 2;
    long gr = rowBase + r;
    long i = (gr < B2) ? gr : (gr - B2);
    float4 za = *(const float4*)&zb[i * 128 + k4];
    float4 zc = *(const float4*)&zb[(i + B2) * 128 + k4];
    float4 bn = *(const float4*)&bnn[k4];
    const float* ap = (gr < B2) ? &aggA[i * 128 + k4] : &aggB[i * 128 + k4];
    float4 ag = *(const float4*)ap;
    float4 xv;
    xv.x = fmaxf(ag.x + za.x + zc.x + bn.x, 0.f);
    xv.y = fmaxf(ag.y + za.y + zc.y + bn.y, 0.f);
    xv.z = fmaxf(ag.z + za.z + zc.z + bn.z, 0.f);
    xv.w = fmaxf(ag.w + za.w + zc.w + bn.w, 0.f);
    ushort4 h4, l4;
    h4.x = f2bf(xv.x); l4.x = f2bf(xv.x - bf2f(h4.x));
    h4.y = f2bf(xv.y); l4.y = f2bf(xv.y - bf2f(h4.y));
    h4.z = f2bf(xv.z); l4.z = f2bf(xv.z - bf2f(h4.z));
    h4.w = f2bf(xv.w); l4.w = f2bf(xv.w - bf2f(h4.w));
    *(ushort4*)(A1h + swz256(r, k4 * 2)) = h4;
    *(ushort4*)(A1l + swz256(r, k4 * 2)) = l4;
    float4 pv = *(const float4*)&xp[gr * 128 + k4];
    h4.x = f2bf(pv.x); l4.x = f2bf(pv.x - bf2f(h4.x));
    h4.y = f2bf(pv.y); l4.y = f2bf(pv.y - bf2f(h4.y));
    h4.z = f2bf(pv.z); l4.z = f2bf(pv.z - bf2f(h4.z));
    h4.w = f2bf(pv.w); l4.w = f2bf(pv.w - bf2f(h4.w));
    *(ushort4*)(A2h + swz256(r, k4 * 2)) = h4;
    *(ushort4*)(A2l + swz256(r, k4 * 2)) = l4;
  }
  __syncthreads();

  f32x4 rg = (f32x4){0,0,0,0}, zg = (f32x4){0,0,0,0};

  for (int gate = 0; gate < 3; ++gate) {
    f32x4 gi = (f32x4){0,0,0,0}, gh = (f32x4){0,0,0,0};
    for (int src = 0; src < 2; ++src) {
      const ushort* Wh = src ? Whhh : Wihh;
      const ushort* Wl = src ? Whhl : Wihl;
      const char* Ah = src ? A2h : A1h;
      const char* Al = src ? A2l : A1l;
      for (int k0 = 0; k0 < 128; k0 += 64) {
        __syncthreads();
        {
          int n = tid >> 3, k8 = (tid & 7) << 3;
          long wrow = (long)(gate * 128 + qt * 32 + n);
          *(uint4*)(Bh + swz128(n, k8 * 2)) = *(const uint4*)&Wh[wrow * 128 + k0 + k8];
          *(uint4*)(Bl + swz128(n, k8 * 2)) = *(const uint4*)&Wl[wrow * 128 + k0 + k8];
        }
        __syncthreads();
        f32x4 a = (src == 0) ? gi : gh;
        #pragma unroll
        for (int ks = 0; ks < 2; ++ks) {
          const int ko = ks * 32 + (l >> 4) * 8;
          short8 ah  = *(const short8*)(Ah + swz256(ar, (k0 + ko) * 2));
          short8 al8 = *(const short8*)(Al + swz256(ar, (k0 + ko) * 2));
          const int c = cs * 16 + (l & 15);
          short8 bh  = *(const short8*)(Bh + swz128(c, ko * 2));
          short8 bl8 = *(const short8*)(Bl + swz128(c, ko * 2));
          a = __builtin_amdgcn_mfma_f32_16x16x32_bf16(al8, bh, a, 0, 0, 0);
          a = __builtin_amdgcn_mfma_f32_16x16x32_bf16(ah, bl8, a, 0, 0, 0);
          a = __builtin_amdgcn_mfma_f32_16x16x32_bf16(ah, bh, a, 0, 0, 0);
        }
        if (src == 0) gi = a; else gh = a;
      }
    }
    int cg = qt * 32 + cs * 16 + (l & 15);
    float bi = bih[gate * 128 + cg], bh2 = bhh[gate * 128 + cg];
    #pragma unroll
    for (int i = 0; i < 4; ++i) {
      float a = gi[i] + bi;
      float b = gh[i] + bh2;
      if (gate == 0) {
        rg[i] = 1.f / (1.f + expf(-(a + b)));
      } else if (gate == 1) {
        zg[i] = 1.f / (1.f + expf(-(a + b)));
      } else {
        float ng = tanhf(a + rg[i] * b);
        long row = rowBase + crow + i;
        float h = xp[row * 128 + cg];
        xnew[row * 128 + cg] = (1.f - zg[i]) * ng + zg[i] * h;
      }
    }
  }
}

// ---------------------------------------------------------------------------
// xpzb v2: 32-row tiles, grid 128. Also zeroes aggA/aggB (fused memset).
// xp = relu(xcat@Wp+bp); zb = xp@be2 (xp kept in LDS).
// ---------------------------------------------------------------------------
__global__ __launch_bounds__(256, 3) void xpzb_kernel(
    const float* __restrict__ xcat,
    const ushort* __restrict__ Wph, const ushort* __restrict__ Wpl,
    const float* __restrict__ bp,
    const ushort* __restrict__ be2h, const ushort* __restrict__ be2l,
    float* __restrict__ xp, float* __restrict__ zb,
    float* __restrict__ aggZero)          // 524288 floats to zero
{
  __shared__ __align__(16) char AhB[8192], AlB[8192];
  __shared__ __align__(16) char BhB[16384], BlB[16384];
  const int tid = threadIdx.x;
  const int w = tid >> 6, l = tid & 63;
  const long rowBase = (long)blockIdx.x * 32;
  const int rw = w & 1, ch2 = w >> 1;
  const int ar = rw * 16 + (l & 15);
  const int crow = rw * 16 + ((l >> 4) << 2);

  // fused memset: zero aggA/aggB (consumed by zfold next)
  {
    const float4 z4 = make_float4(0.f, 0.f, 0.f, 0.f);
    long base = (long)(blockIdx.x * 256 + tid) * 4;
    long stride = (long)gridDim.x * 256 * 4;
    for (long t = base; t < 524288; t += stride)
      *(float4*)&aggZero[t] = z4;
  }

  #pragma unroll
  for (int q = 0; q < 4; ++q) {
    int t = tid + 256 * q;
    int r = t >> 5, k4 = (t & 31) << 2;
    float4 v = *(const float4*)&xcat[(rowBase + r) * 128 + k4];
    ushort4 h4, l4;
    h4.x = f2bf(v.x); l4.x = f2bf(v.x - bf2f(h4.x));
    h4.y = f2bf(v.y); l4.y = f2bf(v.y - bf2f(h4.y));
    h4.z = f2bf(v.z); l4.z = f2bf(v.z - bf2f(h4.z));
    h4.w = f2bf(v.w); l4.w = f2bf(v.w - bf2f(h4.w));
    *(ushort4*)(AhB + swz256(r, k4 * 2)) = h4;
    *(ushort4*)(AlB + swz256(r, k4 * 2)) = l4;
  }
  __syncthreads();

  f32x4 acc[4];
  #pragma unroll
  for (int fc = 0; fc < 4; ++fc) acc[fc] = (f32x4){0.f, 0.f, 0.f, 0.f};
  for (int k0 = 0; k0 < 128; k0 += 64) {
    #pragma unroll
    for (int q = 0; q < 4; ++q) {
      int lin = tid + 256 * q;
      int n = lin >> 3, k8 = (lin & 7) << 3;
      *(uint4*)(BhB + swz128(n, k8 * 2)) = *(const uint4*)&Wph[n * 128 + k0 + k8];
      *(uint4*)(BlB + swz128(n, k8 * 2)) = *(const uint4*)&Wpl[n * 128 + k0 + k8];
    }
    __syncthreads();
    #pragma unroll
    for (int ks = 0; ks < 2; ++ks) {
      const int ko = ks * 32 + (l >> 4) * 8;
      short8 ah  = *(const short8*)(AhB + swz256(ar, (k0 + ko) * 2));
      short8 al8 = *(const short8*)(AlB + swz256(ar, (k0 + ko) * 2));
      #pragma unroll
      for (int fc = 0; fc < 4; ++fc) {
        const int c = ch2 * 64 + fc * 16 + (l & 15);
        short8 bh  = *(const short8*)(BhB + swz128(c, ko * 2));
        short8 bl8 = *(const short8*)(BlB + swz128(c, ko * 2));
        acc[fc] = __builtin_amdgcn_mfma_f32_16x16x32_bf16(al8, bh, acc[fc], 0, 0, 0);
        acc[fc] = __builtin_amdgcn_mfma_f32_16x16x32_bf16(ah, bl8, acc[fc], 0, 0, 0);
        acc[fc] = __builtin_amdgcn_mfma_f32_16x16x32_bf16(ah, bh, acc[fc], 0, 0, 0);
      }
    }
    __syncthreads();
  }

  #pragma unroll
  for (int fc = 0; fc < 4; ++fc) {
    int col = ch2 * 64 + fc * 16 + (l & 15);
    float bv = bp[col];
    #pragma unroll
    for (int i = 0; i < 4; ++i) {
      int lr = crow + i;
      float v = fmaxf(acc[fc][i] + bv, 0.f);
      xp[(rowBase + lr) * 128 + col] = v;
      ushort h = f2bf(v);
      *(ushort*)(AhB + swz256(lr, col * 2)) = h;
      *(ushort*)(AlB + swz256(lr, col * 2)) = f2bf(v - bf2f(h));
    }
  }

  #pragma unroll
  for (int fc = 0; fc < 4; ++fc) acc[fc] = (f32x4){0.f, 0.f, 0.f, 0.f};
  for (int k0 = 0; k0 < 128; k0 += 64) {
    __syncthreads();
    #pragma unroll
    for (int q = 0; q < 4; ++q) {
      int lin = tid + 256 * q;
      int n = lin >> 3, k8 = (lin & 7) << 3;
      *(uint4*)(BhB + swz128(n, k8 * 2)) = *(const uint4*)&be2h[n * 128 + k0 + k8];
      *(uint4*)(BlB + swz128(n, k8 * 2)) = *(const uint4*)&be2l[n * 128 + k0 + k8];
    }
    __syncthreads();
    #pragma unroll
    for (int ks = 0; ks < 2; ++ks) {
      const int ko = ks * 32 + (l >> 4) * 8;
      short8 ah  = *(const short8*)(AhB + swz256(ar, (k0 + ko) * 2));
      short8 al8 = *(const short8*)(AlB + swz256(ar, (k0 + ko) * 2));
      #pragma unroll
      for (int fc = 0; fc < 4; ++fc) {
        const int c = ch2 * 64 + fc * 16 + (l & 15);
        short8 bh  = *(const short8*)(BhB + swz128(c, ko * 2));
        short8 bl8 = *(const short8*)(BlB + swz128(c, ko * 2));
        acc[fc] = __builtin_amdgcn_mfma_f32_16x16x32_bf16(al8, bh, acc[fc], 0, 0, 0);
        acc[fc] = __builtin_amdgcn_mfma_f32_16x16x32_bf16(ah, bl8, acc[fc], 0, 0, 0);
        acc[fc] = __builtin_amdgcn_mfma_f32_16x16x32_bf16(ah, bh, acc[fc], 0, 0, 0);
      }
    }
  }
  #pragma unroll
  for (int fc = 0; fc < 4; ++fc) {
    int col = ch2 * 64 + fc * 16 + (l & 15);
    #pragma unroll
    for (int i = 0; i < 4; ++i) {
      int lr = crow + i;
      zb[(rowBase + lr) * 128 + col] = acc[fc][i];
    }
  }
}

// ---------------------------------------------------------------------------
// cls v2 (validated round 20): 32-row tiles, grid 64.
// ---------------------------------------------------------------------------
__global__ __launch_bounds__(256, 2) void cls_kernel(
    const float* __restrict__ xnew,
    const ushort* __restrict__ W1h, const ushort* __restrict__ W1l,
    const float* __restrict__ b1,
    const ushort* __restrict__ W2h, const ushort* __restrict__ W2l,
    const float* __restrict__ b2,
    const float* __restrict__ Wcl3, const float* __restrict__ bcl3,
    float* __restrict__ out)
{
  __shared__ __align__(16) char O1h[8192], O1l[8192];
  __shared__ __align__(16) char AhB[4096], AlB[4096];
  __shared__ __align__(16) char BhB[16384], BlB[16384];
  __shared__ float redP[64];
  const int tid = threadIdx.x;
  const int w = tid >> 6, l = tid & 63;
  const long rowBase = (long)blockIdx.x * 32;
  const int rw = w & 1, ch2 = w >> 1;
  const int ar = rw * 16 + (l & 15);
  const int crow = rw * 16 + ((l >> 4) << 2);
  if (tid < 64) redP[tid] = 0.f;

  f32x4 acc[4];
  #pragma unroll
  for (int fc = 0; fc < 4; ++fc) acc[fc] = (f32x4){0.f, 0.f, 0.f, 0.f};
  for (int k0 = 0; k0 < 256; k0 += 64) {
    const float* Ab = (k0 < 128) ? xnew : (xnew + (long)B2 * 128);
    const int kc = k0 & 127;
    #pragma unroll
    for (int q = 0; q < 2; ++q) {
      int lin = tid + 256 * q;
      int r = lin >> 4, k4 = (lin & 15) << 2;
      float4 v = *(const float4*)&Ab[(rowBase + r) * 128 + kc + k4];
      ushort4 h4, l4;
      h4.x = f2bf(v.x); l4.x = f2bf(v.x - bf2f(h4.x));
      h4.y = f2bf(v.y); l4.y = f2bf(v.y - bf2f(h4.y));
      h4.z = f2bf(v.z); l4.z = f2bf(v.z - bf2f(h4.z));
      h4.w = f2bf(v.w); l4.w = f2bf(v.w - bf2f(h4.w));
      *(ushort4*)(AhB + swz128(r, k4 * 2)) = h4;
      *(ushort4*)(AlB + swz128(r, k4 * 2)) = l4;
    }
    #pragma unroll
    for (int q = 0; q < 4; ++q) {
      int lin = tid + 256 * q;
      int n = lin >> 3, k8 = (lin & 7) << 3;
      *(uint4*)(BhB + swz128(n, k8 * 2)) = *(const uint4*)&W1h[(long)n * 256 + k0 + k8];
      *(uint4*)(BlB + swz128(n, k8 * 2)) = *(const uint4*)&W1l[(long)n * 256 + k0 + k8];
    }
    __syncthreads();
    #pragma unroll
    for (int ks = 0; ks < 2; ++ks) {
      const int ko = ks * 32 + (l >> 4) * 8;
      short8 ah  = *(const short8*)(AhB + swz128(ar, ko * 2));
      short8 al8 = *(const short8*)(AlB + swz128(ar, ko * 2));
      #pragma unroll
      for (int fc = 0; fc < 4; ++fc) {
        const int c = ch2 * 64 + fc * 16 + (l & 15);
        short8 bh  = *(const short8*)(BhB + swz128(c, ko * 2));
        short8 bl8 = *(const short8*)(BlB + swz128(c, ko * 2));
        acc[fc] = __builtin_amdgcn_mfma_f32_16x16x32_bf16(al8, bh, acc[fc], 0, 0, 0);
        acc[fc] = __builtin_amdgcn_mfma_f32_16x16x32_bf16(ah, bl8, acc[fc], 0, 0, 0);
        acc[fc] = __builtin_amdgcn_mfma_f32_16x16x32_bf16(ah, bh, acc[fc], 0, 0, 0);
      }
    }
    __syncthreads();
  }
  #pragma unroll
  for (int fc = 0; fc < 4; ++fc) {
    int col = ch2 * 64 + fc * 16 + (l & 15);
    float bv = b1[col];
    #pragma unroll
    for (int i = 0; i < 4; ++i) {
      int lr = crow + i;
      float v = fmaxf(acc[fc][i] + bv, 0.f);
      ushort h = f2bf(v);
      *(ushort*)(O1h + swz256(lr, col * 2)) = h;
      *(ushort*)(O1l + swz256(lr, col * 2)) = f2bf(v - bf2f(h));
    }
  }

  #pragma unroll
  for (int fc = 0; fc < 4; ++fc) acc[fc] = (f32x4){0.f, 0.f, 0.f, 0.f};
  for (int k0 = 0; k0 < 128; k0 += 64) {
    __syncthreads();
    #pragma unroll
    for (int q = 0; q < 4; ++q) {
      int lin = tid + 256 * q;
      int n = lin >> 3, k8 = (lin & 7) << 3;
      *(uint4*)(BhB + swz128(n, k8 * 2)) = *(const uint4*)&W2h[n * 128 + k0 + k8];
      *(uint4*)(BlB + swz128(n, k8 * 2)) = *(const uint4*)&W2l[n * 128 + k0 + k8];
    }
    __syncthreads();
    #pragma unroll
    for (int ks = 0; ks < 2; ++ks) {
      const int ko = ks * 32 + (l >> 4) * 8;
      short8 ah  = *(const short8*)(O1h + swz256(ar, (k0 + ko) * 2));
      short8 al8 = *(const short8*)(O1l + swz256(ar, (k0 + ko) * 2));
      #pragma unroll
      for (int fc = 0; fc < 4; ++fc) {
        const int c = ch2 * 64 + fc * 16 + (l & 15);
        short8 bh  = *(const short8*)(BhB + swz128(c, ko * 2));
        short8 bl8 = *(const short8*)(BlB + swz128(c, ko * 2));
        acc[fc] = __builtin_amdgcn_mfma_f32_16x16x32_bf16(al8, bh, acc[fc], 0, 0, 0);
        acc[fc] = __builtin_amdgcn_mfma_f32_16x16x32_bf16(ah, bl8, acc[fc], 0, 0, 0);
        acc[fc] = __builtin_amdgcn_mfma_f32_16x16x32_bf16(ah, bh, acc[fc], 0, 0, 0);
      }
    }
  }

  float p0[4] = {0.f, 0.f, 0.f, 0.f}, p1[4] = {0.f, 0.f, 0.f, 0.f};
  #pragma unroll
  for (int fc = 0; fc < 4; ++fc) {
    int col = ch2 * 64 + fc * 16 + (l & 15);
    float bv = b2[col];
    float w0 = Wcl3[col * 2], w1 = Wcl3[col * 2 + 1];
    #pragma unroll
    for (int i = 0; i < 4; ++i) {
      float v = fmaxf(acc[fc][i] + bv, 0.f);
      p0[i] = fmaf(v, w0, p0[i]);
      p1[i] = fmaf(v, w1, p1[i]);
    }
  }
  __syncthreads();
  #pragma unroll
  for (int i = 0; i < 4; ++i) {
    #pragma unroll
    for (int m = 1; m < 16; m <<= 1) {
      p0[i] += __shfl_xor(p0[i], m);
      p1[i] += __shfl_xor(p1[i], m);
    }
    if ((l & 15) == 0) {
      atomicAdd(&redP[(crow + i) * 2 + 0], p0[i]);
      atomicAdd(&redP[(crow + i) * 2 + 1], p1[i]);
    }
  }
  __syncthreads();
  if (tid < 64) {
    int row = tid >> 1, c = tid & 1;
    out[(rowBase + row) * 2 + c] = redP[row * 2 + c] + bcl3[c];
  }
}

// ---------------------------------------------------------------------------
// zfold via MFMA (validated round 8/18 version).
// ---------------------------------------------------------------------------
__global__ __launch_bounds__(256, 1) void zfold_mfma_kernel(
    const float* __restrict__ xp,
    const ushort* __restrict__ We2h, const ushort* __restrict__ We2l,
    const float* __restrict__ interhb, const float* __restrict__ ia1,
    const float* __restrict__ ia2, const float* __restrict__ We1,
    const float* __restrict__ be1,
    float* __restrict__ aggA, float* __restrict__ aggB)
{
  __shared__ __align__(16) ushort Ah[2][64 * 72], Al[2][64 * 72];
  __shared__ __align__(16) ushort Bh[128 * 72], Bl[128 * 72];
  __shared__ float accAs[32 * 128], accBs[32 * 128];
  __shared__ float ehs[3][32][8];
  const int tid = threadIdx.x;
  const int w = tid >> 6, l = tid & 63;
  const int rg = blockIdx.x >> 2, kq = blockIdx.x & 3;
  const int i0 = rg * 32;

  for (int t = tid; t < 2048; t += 256) {
    int r = t >> 5, k4 = (t & 31) << 2;
    int gr = (r < 32) ? (i0 + r) : (B2 + i0 + r - 32);
    float4 v = *(const float4*)&xp[(long)gr * 128 + k4];
    int ch = k4 >> 6, ko = k4 & 63;
    ushort4 h4, l4;
    h4.x = f2bf(v.x); l4.x = f2bf(v.x - bf2f(h4.x));
    h4.y = f2bf(v.y); l4.y = f2bf(v.y - bf2f(h4.y));
    h4.z = f2bf(v.z); l4.z = f2bf(v.z - bf2f(h4.z));
    h4.w = f2bf(v.w); l4.w = f2bf(v.w - bf2f(h4.w));
    *(ushort4*)&Ah[ch][r * 72 + ko] = h4;
    *(ushort4*)&Al[ch][r * 72 + ko] = l4;
  }
  for (int t = tid; t < 768; t += 256) {
    int grp = t >> 8, rem = t & 255;
    int mm = rem >> 3, kk = rem & 7;
    int k = kq * 8 + kk;
    float u = (grp == 0) ? interhb[i0 + mm] : (grp == 1) ? ia1[i0 + mm] : ia2[i0 + mm];
    ehs[grp][mm][kk] = fmaxf(fmaf(u, We1[k], be1[k]), 0.f);
  }
  for (int t = tid; t < 4096; t += 256) { accAs[t] = 0.f; accBs[t] = 0.f; }

  float foldA[8][4] = {{0.f}}, foldB[8][4] = {{0.f}};
  const int ar = w * 16 + (l & 15);

  for (int kk = 0; kk < 8; ++kk) {
    const int k = kq * 8 + kk;
    f32x4 acc[8];
    #pragma unroll
    for (int fc = 0; fc < 8; ++fc) acc[fc] = (f32x4){0.f, 0.f, 0.f, 0.f};
    for (int ch = 0; ch < 2; ++ch) {
      __syncthreads();
      #pragma unroll
      for (int q = 0; q < 4; ++q) {
        int lin = tid + 256 * q;
        int n = lin >> 3, k8 = (lin & 7) << 3;
        *(uint4*)&Bh[n * 72 + k8] = *(const uint4*)&We2h[k * 16384 + n * 128 + ch * 64 + k8];
        *(uint4*)&Bl[n * 72 + k8] = *(const uint4*)&We2l[k * 16384 + n * 128 + ch * 64 + k8];
      }
      __syncthreads();
      #pragma unroll
      for (int ks = 0; ks < 2; ++ks) {
        const int ko = ks * 32 + (l >> 4) * 8;
        short8 ah  = *(const short8*)&Ah[ch][ar * 72 + ko];
        short8 al8 = *(const short8*)&Al[ch][ar * 72 + ko];
        #pragma unroll
        for (int fc = 0; fc < 8; ++fc) {
          const int c = fc * 16 + (l & 15);
          short8 bh  = *(const short8*)&Bh[c * 72 + ko];
          short8 bl8 = *(const short8*)&Bl[c * 72 + ko];
          acc[fc] = __builtin_amdgcn_mfma_f32_16x16x32_bf16(al8, bh, acc[fc], 0, 0, 0);
          acc[fc] = __builtin_amdgcn_mfma_f32_16x16x32_bf16(ah, bl8, acc[fc], 0, 0, 0);
          acc[fc] = __builtin_amdgcn_mfma_f32_16x16x32_bf16(ah, bh, acc[fc], 0, 0, 0);
        }
      }
    }
    #pragma unroll
    for (int i = 0; i < 4; ++i) {
      int lr = w * 16 + ((l >> 4) << 2) + i;
      int m = lr & 31, up = lr >> 5;
      float eA = up ? ehs[0][m][kk] : ehs[1][m][kk];
      float eB = up ? ehs[2][m][kk] : ehs[0][m][kk];
      #pragma unroll
      for (int fc = 0; fc < 8; ++fc) {
        foldA[fc][i] = fmaf(eA, acc[fc][i], foldA[fc][i]);
        foldB[fc][i] = fmaf(eB, acc[fc][i], foldB[fc][i]);
      }
    }
  }
  #pragma unroll
  for (int i = 0; i < 4; ++i) {
    int lr = w * 16 + ((l >> 4) << 2) + i;
    int m = lr & 31;
    #pragma unroll
    for (int fc = 0; fc < 8; ++fc) {
      int c = fc * 16 + (l & 15);
      atomicAdd(&accAs[m * 128 + c], foldA[fc][i]);
      atomicAdd(&accBs[m * 128 + c], foldB[fc][i]);
    }
  }
  __syncthreads();
  for (int t = tid; t < 4096; t += 256) {
    int mm = t >> 7, c = t & 127;
    atomicAdd(&aggA[(long)(i0 + mm) * 128 + c], accAs[t]);
    atomicAdd(&aggB[(long)(i0 + mm) * 128 + c], accBs[t]);
  }
}

// ---------------------------------------------------------------------------
// FULLY-FUSED ALL-MFMA GraphConv, v2: adjacency build woven into the y1-GEMM
// phases via a DEDICATED scratch region (no alias with live A-lo tile).
// Removes 3 serial barrier-phases from the per-block critical path.
// LDS 75264 B -> still 2 blocks/CU.
// ---------------------------------------------------------------------------
__global__ __launch_bounds__(512, 4) void gconv_kernel(
    const float* __restrict__ h1, const float* __restrict__ h2,
    const int* __restrict__ src1, const int* __restrict__ dst1,
    const int* __restrict__ src2, const int* __restrict__ dst2,
    const float* __restrict__ bg1,
    const ushort* __restrict__ W1h, const ushort* __restrict__ W1l,
    const ushort* __restrict__ W2h, const ushort* __restrict__ W2l,
    const float* __restrict__ bias2, const float* __restrict__ s1x,
    float* __restrict__ xcat)
{
  __shared__ __align__(16) char pool[75264];
  char* AhB = pool;
  char* AlB = pool + 16384;
  char* BhB = pool + 32768;
  char* BlB = pool + 49152;
  char* A2h = pool;
  char* A2l = pool + 8192;
  char* Byh = pool + 32768;
  char* Byl = pool + 49152;
  float* cs = (float*)(pool + 65536);
  // DEDICATED adjacency scratch (never aliases live tiles):
  float* cntS = (float*)(pool + 66560);          // [2][990]
  float* rsIS = (float*)(pool + 74752);          // [2][32]
  float* rsOS = (float*)(pool + 75008);          // [2][32]

  const int tid = threadIdx.x;
  const int p = blockIdx.x;
  const int g = p >> 10;
  const int mloc = (p & 1023) * 2;
  const float* hsrc = g ? h2 : h1;
  if (tid < 256) cs[tid] = 0.f;
  // zero adjacency scratch before first barrier (covers cnt + rs regions)
  for (int t = tid; t < 2176; t += 512) cntS[t] = 0.f;

  const int w8 = tid >> 6, l = tid & 63;
  const int rw = w8 & 3;
  const int ch2 = w8 >> 2;
  const int ar = rw * 16 + (l & 15);
  const int crow = rw * 16 + ((l >> 4) << 2);

  // ---- ph0a: stage X into swz256 bf16-split A ----
  #pragma unroll
  for (int q = 0; q < 4; ++q) {
    int lin = tid + 512 * q;
    int r = lin >> 5, k4 = (lin & 31) << 2;
    float4 v = make_float4(0.f, 0.f, 0.f, 0.f);
    if (r < 60) {
      const float* Ar = &hsrc[(long)(mloc * 30 + r) * 74];
      if (k4 + 4 <= 74) {
        float2 a = *(const float2*)&Ar[k4];
        float2 b = *(const float2*)&Ar[k4 + 2];
        v = make_float4(a.x, a.y, b.x, b.y);
      } else if (k4 + 2 <= 74) {
        float2 a = *(const float2*)&Ar[k4];
        v.x = a.x; v.y = a.y;
      }
    }
    ushort4 h4, l4;
    h4.x = f2bf(v.x); l4.x = f2bf(v.x - bf2f(h4.x));
    h4.y = f2bf(v.y); l4.y = f2bf(v.y - bf2f(h4.y));
    h4.z = f2bf(v.z); l4.z = f2bf(v.z - bf2f(h4.z));
    h4.w = f2bf(v.w); l4.w = f2bf(v.w - bf2f(h4.w));
    *(ushort4*)(AhB + swz256(r, k4 * 2)) = h4;
    *(ushort4*)(AlB + swz256(r, k4 * 2)) = l4;
  }
  __syncthreads();   // X staged + scratch zeroed

  // ---- ph0b: y1 = X @ Wg1 (MFMA), with adjacency build woven in ----
  f32x4 acc[4];
  #pragma unroll
  for (int fc = 0; fc < 4; ++fc) acc[fc] = (f32x4){0.f, 0.f, 0.f, 0.f};
  for (int k0 = 0; k0 < 128; k0 += 64) {
    if (k0 == 0 && tid < 2 * EPM) {
      // edge counts (visible after the barrier below)
      int mol = tid / EPM, e = tid - mol * EPM;
      const int* srcp = g ? src2 : src1;
      const int* dstp = g ? dst2 : dst1;
      int m = mloc + mol;
      int s = srcp[m * EPM + e] - m * NPM;
      int d = dstp[m * EPM + e] - m * NPM;
      atomicAdd(&cntS[mol * 990 + d * 33 + s], 1.0f);
    }
    #pragma unroll
    for (int q = 0; q < 2; ++q) {
      int lin = tid + 512 * q;
      int n = lin >> 3, k8 = (lin & 7) << 3;
      *(uint4*)(BhB + swz128(n, k8 * 2)) = *(const uint4*)&W1h[n * 128 + k0 + k8];
      *(uint4*)(BlB + swz128(n, k8 * 2)) = *(const uint4*)&W1l[n * 128 + k0 + k8];
    }
    __syncthreads();   // B ready; edge counts complete (k0==0)
    #pragma unroll
    for (int ks = 0; ks < 2; ++ks) {
      const int ko = ks * 32 + (l >> 4) * 8;
      short8 ah  = *(const short8*)(AhB + swz256(ar, (k0 + ko) * 2));
      short8 al8 = *(const short8*)(AlB + swz256(ar, (k0 + ko) * 2));
      #pragma unroll
      for (int fc = 0; fc < 4; ++fc) {
        const int c = ch2 * 64 + fc * 16 + (l & 15);
        short8 bh  = *(const short8*)(BhB + swz128(c, ko * 2));
        short8 bl8 = *(const short8*)(BlB + swz128(c, ko * 2));
        acc[fc] = __builtin_amdgcn_mfma_f32_16x16x32_bf16(al8, bh, acc[fc], 0, 0, 0);
        acc[fc] = __builtin_amdgcn_mfma_f32_16x16x32_bf16(ah, bl8, acc[fc], 0, 0, 0);
        acc[fc] = __builtin_amdgcn_mfma_f32_16x16x32_bf16(ah, bh, acc[fc], 0, 0, 0);
      }
    }
    if (k0 == 0) {
      // degree sums (read cnt; write rs; consumed after loop's final barrier)
      if (tid < 60) {
        int mol = tid / 30, r = tid - mol * 30;
        float s = 0.f;
        for (int k = 0; k < 30; ++k) s += cntS[mol * 990 + r * 33 + k];
        rsIS[mol * 32 + r] = rsqrtf(fmaxf(s, 1.f));
      } else if (tid >= 64 && tid < 124) {
        int t2 = tid - 64;
        int mol = t2 / 30, sc = t2 - mol * 30;
        float s = 0.f;
        for (int d = 0; d < 30; ++d) s += cntS[mol * 990 + d * 33 + sc];
        rsOS[mol * 32 + sc] = rsqrtf(fmaxf(s, 1.f));
      }
    }
    __syncthreads();
  }

  // ---- ph1: y1 acc -> By B-tile; normalized Abig -> A2 (same phase) ----
  #pragma unroll
  for (int fc = 0; fc < 4; ++fc) {
    int n = ch2 * 64 + fc * 16 + (l & 15);
    ushort4 h4, l4;
    h4.x = f2bf(acc[fc][0]); l4.x = f2bf(acc[fc][0] - bf2f(h4.x));
    h4.y = f2bf(acc[fc][1]); l4.y = f2bf(acc[fc][1] - bf2f(h4.y));
    h4.z = f2bf(acc[fc][2]); l4.z = f2bf(acc[fc][2] - bf2f(h4.z));
    h4.w = f2bf(acc[fc][3]); l4.w = f2bf(acc[fc][3] - bf2f(h4.w));
    *(ushort4*)(Byh + swz128(n, crow * 2)) = h4;
    *(ushort4*)(Byl + swz128(n, crow * 2)) = l4;
  }
  for (int t = tid; t < 4096; t += 512) {
    int row = t >> 6, k = t & 63;
    float v = 0.f;
    if (row < 30) {
      if (k < 30) v = cntS[row * 33 + k] * rsIS[row] * rsOS[k];
    } else if (row < 60) {
      if (k >= 30 && k < 60)
        v = cntS[990 + (row - 30) * 33 + (k - 30)] * rsIS[32 + row - 30] * rsOS[32 + k - 30];
    }
    ushort h = f2bf(v);
    *(ushort*)(A2h + swz128(row, k * 2)) = h;
    *(ushort*)(A2l + swz128(row, k * 2)) = f2bf(v - bf2f(h));
  }
  __syncthreads();

  // ---- ph2: t1 = relu(Abig@By + b1) (MFMA, K=64) ----
  f32x4 acc2[4];
  #pragma unroll
  for (int fc = 0; fc < 4; ++fc) acc2[fc] = (f32x4){0.f, 0.f, 0.f, 0.f};
  #pragma unroll
  for (int ks = 0; ks < 2; ++ks) {
    const int ko = ks * 32 + (l >> 4) * 8;
    short8 ah  = *(const short8*)(A2h + swz128(ar, ko * 2));
    short8 al8 = *(const short8*)(A2l + swz128(ar, ko * 2));
    #pragma unroll
    for (int fc = 0; fc < 4; ++fc) {
      const int c = ch2 * 64 + fc * 16 + (l & 15);
      short8 bh  = *(const short8*)(Byh + swz128(c, ko * 2));
      short8 bl8 = *(const short8*)(Byl + swz128(c, ko * 2));
      acc2[fc] = __builtin_amdgcn_mfma_f32_16x16x32_bf16(al8, bh, acc2[fc], 0, 0, 0);
      acc2[fc] = __builtin_amdgcn_mfma_f32_16x16x32_bf16(ah, bl8, acc2[fc], 0, 0, 0);
      acc2[fc] = __builtin_amdgcn_mfma_f32_16x16x32_bf16(ah, bh, acc2[fc], 0, 0, 0);
    }
  }
  __syncthreads();

  #pragma unroll
  for (int fc = 0; fc < 4; ++fc) {
    int n = ch2 * 64 + fc * 16 + (l & 15);
    float bv = bg1[n];
    float t0 = fmaxf(acc2[fc][0] + bv, 0.f);
    float t1v = fmaxf(acc2[fc][1] + bv, 0.f);
    float t2v = fmaxf(acc2[fc][2] + bv, 0.f);
    float t3 = fmaxf(acc2[fc][3] + bv, 0.f);
    ushort4 h4, l4;
    h4.x = f2bf(t0); l4.x = f2bf(t0 - bf2f(h4.x));
    h4.y = f2bf(t1v); l4.y = f2bf(t1v - bf2f(h4.y));
    h4.z = f2bf(t2v); l4.z = f2bf(t2v - bf2f(h4.z));
    h4.w = f2bf(t3); l4.w = f2bf(t3 - bf2f(h4.w));
    *(ushort4*)(Byh + swz128(n, crow * 2)) = h4;
    *(ushort4*)(Byl + swz128(n, crow * 2)) = l4;
  }
  __syncthreads();

  #pragma unroll
  for (int fc = 0; fc < 4; ++fc) acc2[fc] = (f32x4){0.f, 0.f, 0.f, 0.f};
  #pragma unroll
  for (int ks = 0; ks < 2; ++ks) {
    const int ko = ks * 32 + (l >> 4) * 8;
    short8 ah  = *(const short8*)(A2h + swz128(ar, ko * 2));
    short8 al8 = *(const short8*)(A2l + swz128(ar, ko * 2));
    #pragma unroll
    for (int fc = 0; fc < 4; ++fc) {
      const int c = ch2 * 64 + fc * 16 + (l & 15);
      short8 bh  = *(const short8*)(Byh + swz128(c, ko * 2));
      short8 bl8 = *(const short8*)(Byl + swz128(c, ko * 2));
      acc2[fc] = __builtin_amdgcn_mfma_f32_16x16x32_bf16(al8, bh, acc2[fc], 0, 0, 0);
      acc2[fc] = __builtin_amdgcn_mfma_f32_16x16x32_bf16(ah, bl8, acc2[fc], 0, 0, 0);
      acc2[fc] = __builtin_amdgcn_mfma_f32_16x16x32_bf16(ah, bh, acc2[fc], 0, 0, 0);
    }
  }
  __syncthreads();

  #pragma unroll
  for (int fc = 0; fc < 4; ++fc) {
    int n = ch2 * 64 + fc * 16 + (l & 15);
    #pragma unroll
    for (int i = 0; i < 4; ++i) {
      int r = crow + i;
      ushort h = f2bf(acc2[fc][i]);
      *(ushort*)(AhB + swz256(r, n * 2)) = h;
      *(ushort*)(AlB + swz256(r, n * 2)) = f2bf(acc2[fc][i] - bf2f(h));
    }
  }

  #pragma unroll
  for (int fc = 0; fc < 4; ++fc) acc[fc] = (f32x4){0.f, 0.f, 0.f, 0.f};
  for (int k0 = 0; k0 < 128; k0 += 64) {
    __syncthreads();
    #pragma unroll
    for (int q = 0; q < 2; ++q) {
      int lin = tid + 512 * q;
      int n = lin >> 3, k8 = (lin & 7) << 3;
      *(uint4*)(BhB + swz128(n, k8 * 2)) = *(const uint4*)&W2h[n * 128 + k0 + k8];
      *(uint4*)(BlB + swz128(n, k8 * 2)) = *(const uint4*)&W2l[n * 128 + k0 + k8];
    }
    __syncthreads();
    #pragma unroll
    for (int ks = 0; ks < 2; ++ks) {
      const int ko = ks * 32 + (l >> 4) * 8;
      short8 ah  = *(const short8*)(AhB + swz256(ar, (k0 + ko) * 2));
      short8 al8 = *(const short8*)(AlB + swz256(ar, (k0 + ko) * 2));
      #pragma unroll
      for (int fc = 0; fc < 4; ++fc) {
        const int c = ch2 * 64 + fc * 16 + (l & 15);
        short8 bh  = *(const short8*)(BhB + swz128(c, ko * 2));
        short8 bl8 = *(const short8*)(BlB + swz128(c, ko * 2));
        acc[fc] = __builtin_amdgcn_mfma_f32_16x16x32_bf16(al8, bh, acc[fc], 0, 0, 0);
        acc[fc] = __builtin_amdgcn_mfma_f32_16x16x32_bf16(ah, bl8, acc[fc], 0, 0, 0);
        acc[fc] = __builtin_amdgcn_mfma_f32_16x16x32_bf16(ah, bh, acc[fc], 0, 0, 0);
      }
    }
  }
  __syncthreads();

  #pragma unroll
  for (int fc = 0; fc < 4; ++fc) {
    int col = ch2 * 64 + fc * 16 + (l & 15);
    float bv = bias2[col];
    float s0 = 0.f, s1 = 0.f;
    #pragma unroll
    for (int i = 0; i < 4; ++i) {
      int lr = crow + i;
      if (lr < 60) {
        float v = fmaxf(acc[fc][i] + bv, 0.f);
        if (lr < NPM) s0 += v; else s1 += v;
      }
    }
    s0 += __shfl_down(s0, 32); s0 += __shfl_down(s0, 16);
    s1 += __shfl_down(s1, 32); s1 += __shfl_down(s1, 16);
    if ((l >> 4) == 0) {
      atomicAdd(&cs[col], s0);
      atomicAdd(&cs[128 + col], s1);
    }
  }
  __syncthreads();
  if (tid < 256) {
    int moll = tid >> 7, c = tid & 127;
    int gm = p * 2 + moll;
    int gg = gm >> 11, mm = gm & 2047;
    float sf = gg ? (1.f - s1x[mm]) : s1x[mm];
    xcat[(long)gm * 128 + c] = cs[moll * 128 + c] * (1.f / 30.f) * sf;
  }
}

// ---------------------------------------------------------------------------
extern "C" void kernel_launch(void* const* d_in, const int* in_sizes, int n_in,
                              void* d_out, int out_size, void* d_ws, size_t ws_size,
                              hipStream_t stream)
{
  const float* h1   = (const float*)d_in[0];
  const float* h2   = (const float*)d_in[1];
  const float* s1x  = (const float*)d_in[2];
  const float* ihb  = (const float*)d_in[3];
  const float* ia1  = (const float*)d_in[4];
  const float* ia2  = (const float*)d_in[5];
  const float* Wg1  = (const float*)d_in[6];
  const float* bg1  = (const float*)d_in[7];
  const float* Wg2  = (const float*)d_in[8];
  const float* bg2  = (const float*)d_in[9];
  const float* Wp   = (const float*)d_in[10];
  const float* bp   = (const float*)d_in[11];
  const float* We1  = (const float*)d_in[12];
  const float* be1  = (const float*)d_in[13];
  const float* We2  = (const float*)d_in[14];
  const float* be2  = (const float*)d_in[15];
  const float* bnn  = (const float*)d_in[16];
  const float* Wih  = (const float*)d_in[17];
  const float* bih  = (const float*)d_in[18];
  const float* Whh  = (const float*)d_in[19];
  const float* bhh  = (const float*)d_in[20];
  const float* Wcl1 = (const float*)d_in[21];
  const float* bcl1 = (const float*)d_in[22];
  const float* Wcl2 = (const float*)d_in[23];
  const float* bcl2 = (const float*)d_in[24];
  const float* Wcl3 = (const float*)d_in[25];
  const float* bcl3 = (const float*)d_in[26];
  const int*   src1 = (const int*)d_in[27];
  const int*   dst1 = (const int*)d_in[28];
  const int*   src2 = (const int*)d_in[29];
  const int*   dst2 = (const int*)d_in[30];
  float* out = (float*)d_out;
  float* ws  = (float*)d_ws;

  float* dwn  = ws + 35389440;

  float* xcat = dwn;
  float* xp   = dwn + 524288;
  float* zb   = dwn + 1048576;
  float* aggA = dwn + 1572864;
  float* aggB = dwn + 1835008;
  float* xnew = dwn + 2097152;

  ushort* wt     = (ushort*)(dwn + 6815744);
  ushort* WpTh   = wt;               ushort* WpTl   = wt + 16384;
  ushort* be2Th  = wt + 32768;       ushort* be2Tl  = wt + 49152;
  ushort* WihTh  = wt + 65536;       ushort* WihTl  = wt + 114688;
  ushort* WhhTh  = wt + 163840;      ushort* WhhTl  = wt + 212992;
  ushort* Wcl1Th = wt + 262144;      ushort* Wcl1Tl = wt + 294912;
  ushort* Wcl2Th = wt + 327680;      ushort* Wcl2Tl = wt + 344064;
  ushort* Wg1Th  = wt + 360448;      ushort* Wg1Tl  = wt + 376832;
  ushort* Wg2Th  = wt + 393216;      ushort* Wg2Tl  = wt + 409600;
  ushort* We2h   = wt + 425984;      ushort* We2l   = wt + 950272;

  // ---- fused weight prep (9 weights incl. We2, one launch) ----
  PrepDescs pd;
  const float* Ws_[9]  = {Wp, be2, Wih, Whh, Wcl1, Wcl2, Wg1, Wg2, We2};
  ushort* his[9]       = {WpTh, be2Th, WihTh, WhhTh, Wcl1Th, Wcl2Th, Wg1Th, Wg2Th, We2h};
  ushort* los[9]       = {WpTl, be2Tl, WihTl, WhhTl, Wcl1Tl, Wcl2Tl, Wg1Tl, Wg2Tl, We2l};
  int kr[9]   = {128, 128, 128, 128, 256, 128, 74, 128, 0};
  int kp[9]   = {128, 128, 128, 128, 256, 128, 128, 128, 0};
  int nn[9]   = {128, 128, 384, 384, 128, 128, 128, 128, 0};
  int acc_blk = 0;
  for (int i = 0; i < 8; ++i) {
    pd.W[i] = Ws_[i]; pd.hi[i] = his[i]; pd.lo[i] = los[i];
    pd.Kreal[i] = kr[i]; pd.Kpad[i] = kp[i]; pd.N[i] = nn[i];
    pd.blk0[i] = acc_blk;
    acc_blk += (nn[i] * (kp[i] >> 3) + 255) / 256;
  }
  pd.W[8] = Ws_[8]; pd.hi[8] = his[8]; pd.lo[8] = los[8];
  pd.Kreal[8] = 0; pd.Kpad[8] = 0; pd.N[8] = 0;
  pd.blk0[8] = acc_blk;
  acc_blk += 256;                      // We2: 65536 threads / 256
  pd.blk0[9] = acc_blk;
  prep_all_kernel<<<acc_blk, 256, 0, stream>>>(pd);

  // ---- fully-fused GraphConv (adjacency built in-block, woven) ----
  gconv_kernel<<<2048, 512, 0, stream>>>(h1, h2, src1, dst1, src2, dst2,
                                         bg1, Wg1Th, Wg1Tl, Wg2Th, Wg2Tl,
                                         bg2, s1x, xcat);

  // ---- solvent-system MPNN + fused GRU + classifier ----
  xpzb_kernel<<<128, 256, 0, stream>>>(xcat, WpTh, WpTl, bp, be2Th, be2Tl,
                                       xp, zb, aggA);
  zfold_mfma_kernel<<<256, 256, 0, stream>>>(xp, We2h, We2l, ihb, ia1, ia2,
                                             We1, be1, aggA, aggB);
  grufuse_kernel<<<512, 256, 0, stream>>>(aggA, aggB, zb, bnn, xp,
                                          WihTh, WihTl, bih, WhhTh, WhhTl, bhh,
                                          xnew);
  cls_kernel<<<64, 256, 0, stream>>>(xnew, Wcl1Th, Wcl1Tl, bcl1,
                                     Wcl2Th, Wcl2Tl, bcl2, Wcl3, bcl3, out);
}